// Round 1
// baseline (1214.479 us; speedup 1.0000x reference)
//
#include <hip/hip_runtime.h>
#include <hip/hip_bf16.h>

#define GRID14 14
#define SS 196
#define EE 768
#define HH 4
#define HD 192
#define BB 64
#define MM (BB*SS)       // 12544
#define SE (SS*EE)       // 150528

typedef __bf16 bf16x8 __attribute__((ext_vector_type(8)));
typedef float floatx4 __attribute__((ext_vector_type(4)));

__device__ __forceinline__ float b2f(unsigned int u) {
  union { unsigned int i; float f; } x; x.i = u << 16; return x.f;
}

// ---------------- patch extraction: x[64,3,224,224] f32 -> patches[12544,768] bf16
__global__ __launch_bounds__(256) void patch_kernel(const float* __restrict__ x,
                                                    __hip_bfloat16* __restrict__ p) {
  int idx = blockIdx.x * 256 + threadIdx.x;   // < 12544*768
  int k = idx % EE;
  int m = idx / EE;
  int b = m / SS, s = m % SS;
  int gy = s / GRID14, gx = s % GRID14;
  int c = k >> 8, rem = k & 255, py = rem >> 4, px = rem & 15;
  size_t xi = ((size_t)(b*3 + c)*224 + gy*16 + py)*224 + gx*16 + px;
  p[idx] = __float2bfloat16(x[xi]);
}

// ---------------- weight conversion + QKV weight/bias concat
__global__ __launch_bounds__(256) void convert_weights(
    const float* __restrict__ cw, const float* __restrict__ wq,
    const float* __restrict__ wk, const float* __restrict__ wv,
    const float* __restrict__ wo, const float* __restrict__ bq,
    const float* __restrict__ bk, const float* __restrict__ bv,
    __hip_bfloat16* __restrict__ cw_b, __hip_bfloat16* __restrict__ qkvw_b,
    __hip_bfloat16* __restrict__ wo_b, float* __restrict__ qkv_bias) {
  int i = blockIdx.x * 256 + threadIdx.x;
  const int WN = EE * EE;
  if (i < WN) {
    cw_b[i] = __float2bfloat16(cw[i]);
    wo_b[i] = __float2bfloat16(wo[i]);
    qkvw_b[i]        = __float2bfloat16(wq[i]);
    qkvw_b[WN + i]   = __float2bfloat16(wk[i]);
    qkvw_b[2*WN + i] = __float2bfloat16(wv[i]);
  }
  if (i < EE) { qkv_bias[i] = bq[i]; qkv_bias[EE+i] = bk[i]; qkv_bias[2*EE+i] = bv[i]; }
}

// ---------------- bf16 MFMA GEMM: out[M,N] = A[M,K] @ W[N,K]^T + bias (+skip)
// 128x128 tile, 4 waves in 2x2, each wave 4x4 of 16x16x32 MFMA tiles.
__global__ __launch_bounds__(256, 2) void gemm_bt(
    const __hip_bfloat16* __restrict__ A, const __hip_bfloat16* __restrict__ W,
    const float* __restrict__ bias, const float* __restrict__ skip,
    float* __restrict__ outF, __hip_bfloat16* __restrict__ outB,
    int M, int N, int K) {
  __shared__ __align__(16) unsigned short As[128][32];
  __shared__ __align__(16) unsigned short Bs[128][32];
  const int tid  = threadIdx.x;
  const int lane = tid & 63;
  const int wave = tid >> 6;
  const int wrow = (wave >> 1) * 64;
  const int wcol = (wave & 1) * 64;
  const int tileM = blockIdx.y * 128;
  const int tileN = blockIdx.x * 128;
  const int lm = lane & 15;
  const int lk = (lane >> 4) * 8;
  // staging: slot = tid (+256): row = slot>>2, col = (slot&3)*8 bf16
  const int r0 = tid >> 2, c0 = (tid & 3) * 8;

  floatx4 acc[4][4];
  #pragma unroll
  for (int i = 0; i < 4; ++i)
    #pragma unroll
    for (int j = 0; j < 4; ++j) acc[i][j] = (floatx4)0.0f;

  for (int k0 = 0; k0 < K; k0 += 32) {
    uint4 a0 = *(const uint4*)(A + (size_t)(tileM + r0) * K + k0 + c0);
    uint4 a1 = *(const uint4*)(A + (size_t)(tileM + 64 + r0) * K + k0 + c0);
    uint4 b0 = *(const uint4*)(W + (size_t)(tileN + r0) * K + k0 + c0);
    uint4 b1 = *(const uint4*)(W + (size_t)(tileN + 64 + r0) * K + k0 + c0);
    __syncthreads();
    *(uint4*)&As[r0][c0]      = a0;
    *(uint4*)&As[64 + r0][c0] = a1;
    *(uint4*)&Bs[r0][c0]      = b0;
    *(uint4*)&Bs[64 + r0][c0] = b1;
    __syncthreads();
    bf16x8 af[4], bfr[4];
    #pragma unroll
    for (int i = 0; i < 4; ++i) af[i]  = *(const bf16x8*)&As[wrow + i*16 + lm][lk];
    #pragma unroll
    for (int j = 0; j < 4; ++j) bfr[j] = *(const bf16x8*)&Bs[wcol + j*16 + lm][lk];
    #pragma unroll
    for (int i = 0; i < 4; ++i)
      #pragma unroll
      for (int j = 0; j < 4; ++j)
        acc[i][j] = __builtin_amdgcn_mfma_f32_16x16x32_bf16(af[i], bfr[j], acc[i][j], 0, 0, 0);
  }

  const int rq = (lane >> 4) * 4;
  #pragma unroll
  for (int j = 0; j < 4; ++j) {
    int n = tileN + wcol + j*16 + lm;
    float bj = bias[n];
    #pragma unroll
    for (int i = 0; i < 4; ++i) {
      int mb = tileM + wrow + i*16 + rq;
      #pragma unroll
      for (int r = 0; r < 4; ++r) {
        size_t o = (size_t)(mb + r) * N + n;
        float v = acc[i][j][r] + bj;
        if (skip) v += skip[o];
        if (outF) outF[o] = v;
        else      outB[o] = __float2bfloat16(v);
      }
    }
  }
}

// ---------------- LayerNorm over [S,E] per batch sample (one block per sample)
__global__ __launch_bounds__(256) void ln_kernel(
    const float* __restrict__ in, const float* __restrict__ w,
    const float* __restrict__ bias, __hip_bfloat16* __restrict__ outB,
    float* __restrict__ outF) {
  int bidx = blockIdx.x;
  const float4* xp = (const float4*)(in + (size_t)bidx * SE);
  float s = 0.f, ss = 0.f;
  for (int i = threadIdx.x; i < SE/4; i += 256) {
    float4 v = xp[i];
    s  += v.x + v.y + v.z + v.w;
    ss += v.x*v.x + v.y*v.y + v.z*v.z + v.w*v.w;
  }
  #pragma unroll
  for (int off = 32; off; off >>= 1) { s += __shfl_down(s, off); ss += __shfl_down(ss, off); }
  __shared__ float r1[4], r2[4];
  int wv = threadIdx.x >> 6;
  if ((threadIdx.x & 63) == 0) { r1[wv] = s; r2[wv] = ss; }
  __syncthreads();
  float S1 = r1[0] + r1[1] + r1[2] + r1[3];
  float S2 = r2[0] + r2[1] + r2[2] + r2[3];
  float mu = S1 * (1.0f / SE);
  float var = S2 * (1.0f / SE) - mu * mu;
  float rstd = rsqrtf(var + 1e-5f);
  const float4* wp = (const float4*)w;
  const float4* bp = (const float4*)bias;
  for (int i = threadIdx.x; i < SE/4; i += 256) {
    float4 v = xp[i], wv4 = wp[i], bv4 = bp[i];
    float4 r;
    r.x = (v.x - mu) * rstd * wv4.x + bv4.x;
    r.y = (v.y - mu) * rstd * wv4.y + bv4.y;
    r.z = (v.z - mu) * rstd * wv4.z + bv4.z;
    r.w = (v.w - mu) * rstd * wv4.w + bv4.w;
    if (outF) {
      ((float4*)(outF + (size_t)bidx * SE))[i] = r;
    } else {
      __hip_bfloat16* ob = outB + (size_t)bidx * SE + (size_t)i * 4;
      ob[0] = __float2bfloat16(r.x); ob[1] = __float2bfloat16(r.y);
      ob[2] = __float2bfloat16(r.z); ob[3] = __float2bfloat16(r.w);
    }
  }
}

// ---------------- attention: one block per (b,h,q-row); qkv[12544,2304] bf16
__global__ __launch_bounds__(256) void attn_kernel(const __hip_bfloat16* __restrict__ qkv,
                                                   __hip_bfloat16* __restrict__ o) {
  int sq = blockIdx.x, h = blockIdx.y, b = blockIdx.z;
  int tid = threadIdx.x;
  __shared__ float qs[HD];
  __shared__ float ps[256];
  __shared__ float red[8];
  const __hip_bfloat16* qrow = qkv + (size_t)(b*SS + sq) * 2304 + h * HD;
  if (tid < HD) qs[tid] = __bfloat162float(qrow[tid]) * 0.07216878364870323f; // 1/sqrt(192)
  __syncthreads();
  float sc = -1e30f;
  if (tid < SS) {
    const uint4* kv = (const uint4*)(qkv + (size_t)(b*SS + tid) * 2304 + EE + h * HD);
    float acc = 0.f;
    #pragma unroll
    for (int d8 = 0; d8 < HD/8; ++d8) {
      uint4 u = kv[d8];
      const float* q8 = &qs[d8*8];
      acc += q8[0]*b2f(u.x & 0xffffu) + q8[1]*b2f(u.x >> 16)
           + q8[2]*b2f(u.y & 0xffffu) + q8[3]*b2f(u.y >> 16)
           + q8[4]*b2f(u.z & 0xffffu) + q8[5]*b2f(u.z >> 16)
           + q8[6]*b2f(u.w & 0xffffu) + q8[7]*b2f(u.w >> 16);
    }
    sc = acc;
  }
  float mx = sc;
  #pragma unroll
  for (int off = 32; off; off >>= 1) mx = fmaxf(mx, __shfl_down(mx, off));
  if ((tid & 63) == 0) red[tid >> 6] = mx;
  __syncthreads();
  float gmax = fmaxf(fmaxf(red[0], red[1]), fmaxf(red[2], red[3]));
  float p = (tid < SS) ? __expf(sc - gmax) : 0.f;
  ps[tid] = p;
  float sum = p;
  #pragma unroll
  for (int off = 32; off; off >>= 1) sum += __shfl_down(sum, off);
  if ((tid & 63) == 0) red[4 + (tid >> 6)] = sum;
  __syncthreads();
  float inv = 1.0f / (red[4] + red[5] + red[6] + red[7]);
  if (tid < HD) {
    const __hip_bfloat16* vb = qkv + (size_t)(b*SS) * 2304 + 2*EE + h * HD + tid;
    float acc = 0.f;
    #pragma unroll 4
    for (int k = 0; k < SS; ++k) acc += ps[k] * __bfloat162float(vb[(size_t)k * 2304]);
    o[(size_t)(b*SS + sq) * EE + h * HD + tid] = __float2bfloat16(acc * inv);
  }
}

extern "C" void kernel_launch(void* const* d_in, const int* in_sizes, int n_in,
                              void* d_out, int out_size, void* d_ws, size_t ws_size,
                              hipStream_t stream) {
  const float* x      = (const float*)d_in[0];
  const float* conv_w = (const float*)d_in[1];
  const float* conv_b = (const float*)d_in[2];
  const float* wq = (const float*)d_in[3];
  const float* bq = (const float*)d_in[4];
  const float* wk = (const float*)d_in[5];
  const float* bk = (const float*)d_in[6];
  const float* wv = (const float*)d_in[7];
  const float* bv = (const float*)d_in[8];
  const float* wo = (const float*)d_in[9];
  const float* bo = (const float*)d_in[10];
  const float* ln1w = (const float*)d_in[11];
  const float* ln1b = (const float*)d_in[12];
  const float* ln2w = (const float*)d_in[13];
  const float* ln2b = (const float*)d_in[14];
  float* out = (float*)d_out;

  char* ws = (char*)d_ws;
  __hip_bfloat16* patches = (__hip_bfloat16*)(ws);                // 19267584 B
  __hip_bfloat16* cw_b    = (__hip_bfloat16*)(ws + 19267584);     //  1179648
  __hip_bfloat16* qkvw_b  = (__hip_bfloat16*)(ws + 20447232);     //  3538944
  __hip_bfloat16* wo_b    = (__hip_bfloat16*)(ws + 23986176);     //  1179648
  float*          qkv_b   = (float*)         (ws + 25165824);     //     9216
  float*          emb     = (float*)         (ws + 25175040);     // 38535168
  __hip_bfloat16* hbuf    = (__hip_bfloat16*)(ws + 63710208);     // 19267584
  __hip_bfloat16* qkv     = (__hip_bfloat16*)(ws + 82977792);     // 57802752
  __hip_bfloat16* obuf    = (__hip_bfloat16*)(ws + 140780544);    // 19267584
  // total 160048128 B

  convert_weights<<<2304, 256, 0, stream>>>(conv_w, wq, wk, wv, wo, bq, bk, bv,
                                            cw_b, qkvw_b, wo_b, qkv_b);
  patch_kernel<<<MM*EE/256, 256, 0, stream>>>(x, patches);
  // emb = patches @ conv_w^T + conv_b   (fp32 out, kept as skip1)
  gemm_bt<<<dim3(6, 98), 256, 0, stream>>>(patches, cw_b, conv_b, nullptr, emb, nullptr,
                                           MM, EE, EE);
  // h = LN1(emb) -> bf16
  ln_kernel<<<BB, 256, 0, stream>>>(emb, ln1w, ln1b, hbuf, nullptr);
  // qkv = h @ [wq;wk;wv]^T + [bq;bk;bv]  -> bf16 [12544, 2304]
  gemm_bt<<<dim3(18, 98), 256, 0, stream>>>(hbuf, qkvw_b, qkv_b, nullptr, nullptr, qkv,
                                            MM, 3*EE, EE);
  attn_kernel<<<dim3(SS, HH, BB), 256, 0, stream>>>(qkv, obuf);
  // out_pre = obuf @ wo^T + bo + emb    (fp32, into d_out)
  gemm_bt<<<dim3(6, 98), 256, 0, stream>>>(obuf, wo_b, bo, emb, out, nullptr,
                                           MM, EE, EE);
  // final = LN2(out_pre) in-place
  ln_kernel<<<BB, 256, 0, stream>>>(out, ln2w, ln2b, nullptr, out);
}

// Round 2
// 385.423 us; speedup vs baseline: 3.1510x; 3.1510x over previous
//
#include <hip/hip_runtime.h>
#include <hip/hip_bf16.h>

#define GRID14 14
#define SS 196
#define EE 768
#define HH 4
#define HD 192
#define BB 64
#define MM (BB*SS)       // 12544
#define SE (SS*EE)       // 150528

typedef __bf16 bf16x8 __attribute__((ext_vector_type(8)));
typedef __bf16 bf16x4 __attribute__((ext_vector_type(4)));
typedef float floatx4 __attribute__((ext_vector_type(4)));

// ---------------- patch extraction: x[64,3,224,224] f32 -> patches[12544,768] bf16
__global__ __launch_bounds__(256) void patch_kernel(const float* __restrict__ x,
                                                    __hip_bfloat16* __restrict__ p) {
  int idx = blockIdx.x * 256 + threadIdx.x;   // < 12544*768
  int k = idx % EE;
  int m = idx / EE;
  int b = m / SS, s = m % SS;
  int gy = s / GRID14, gx = s % GRID14;
  int c = k >> 8, rem = k & 255, py = rem >> 4, px = rem & 15;
  size_t xi = ((size_t)(b*3 + c)*224 + gy*16 + py)*224 + gx*16 + px;
  p[idx] = __float2bfloat16(x[xi]);
}

// ---------------- weight conversion + QKV weight/bias concat
__global__ __launch_bounds__(256) void convert_weights(
    const float* __restrict__ cw, const float* __restrict__ wq,
    const float* __restrict__ wk, const float* __restrict__ wv,
    const float* __restrict__ wo, const float* __restrict__ bq,
    const float* __restrict__ bk, const float* __restrict__ bv,
    __hip_bfloat16* __restrict__ cw_b, __hip_bfloat16* __restrict__ qkvw_b,
    __hip_bfloat16* __restrict__ wo_b, float* __restrict__ qkv_bias) {
  int i = blockIdx.x * 256 + threadIdx.x;
  const int WN = EE * EE;
  if (i < WN) {
    cw_b[i] = __float2bfloat16(cw[i]);
    wo_b[i] = __float2bfloat16(wo[i]);
    qkvw_b[i]        = __float2bfloat16(wq[i]);
    qkvw_b[WN + i]   = __float2bfloat16(wk[i]);
    qkvw_b[2*WN + i] = __float2bfloat16(wv[i]);
  }
  if (i < EE) { qkv_bias[i] = bq[i]; qkv_bias[EE+i] = bk[i]; qkv_bias[2*EE+i] = bv[i]; }
}

// ---------------- bf16 MFMA GEMM: out[M,N] = A[M,K] @ W[N,K]^T + bias (+skip)
__global__ __launch_bounds__(256, 2) void gemm_bt(
    const __hip_bfloat16* __restrict__ A, const __hip_bfloat16* __restrict__ W,
    const float* __restrict__ bias, const float* __restrict__ skip,
    float* __restrict__ outF, __hip_bfloat16* __restrict__ outB,
    int M, int N, int K) {
  __shared__ __align__(16) unsigned short As[128][32];
  __shared__ __align__(16) unsigned short Bs[128][32];
  const int tid  = threadIdx.x;
  const int lane = tid & 63;
  const int wave = tid >> 6;
  const int wrow = (wave >> 1) * 64;
  const int wcol = (wave & 1) * 64;
  const int tileM = blockIdx.y * 128;
  const int tileN = blockIdx.x * 128;
  const int lm = lane & 15;
  const int lk = (lane >> 4) * 8;
  const int r0 = tid >> 2, c0 = (tid & 3) * 8;

  floatx4 acc[4][4];
  #pragma unroll
  for (int i = 0; i < 4; ++i)
    #pragma unroll
    for (int j = 0; j < 4; ++j) acc[i][j] = (floatx4)0.0f;

  for (int k0 = 0; k0 < K; k0 += 32) {
    uint4 a0 = *(const uint4*)(A + (size_t)(tileM + r0) * K + k0 + c0);
    uint4 a1 = *(const uint4*)(A + (size_t)(tileM + 64 + r0) * K + k0 + c0);
    uint4 b0 = *(const uint4*)(W + (size_t)(tileN + r0) * K + k0 + c0);
    uint4 b1 = *(const uint4*)(W + (size_t)(tileN + 64 + r0) * K + k0 + c0);
    __syncthreads();
    *(uint4*)&As[r0][c0]      = a0;
    *(uint4*)&As[64 + r0][c0] = a1;
    *(uint4*)&Bs[r0][c0]      = b0;
    *(uint4*)&Bs[64 + r0][c0] = b1;
    __syncthreads();
    bf16x8 af[4], bfr[4];
    #pragma unroll
    for (int i = 0; i < 4; ++i) af[i]  = *(const bf16x8*)&As[wrow + i*16 + lm][lk];
    #pragma unroll
    for (int j = 0; j < 4; ++j) bfr[j] = *(const bf16x8*)&Bs[wcol + j*16 + lm][lk];
    #pragma unroll
    for (int i = 0; i < 4; ++i)
      #pragma unroll
      for (int j = 0; j < 4; ++j)
        acc[i][j] = __builtin_amdgcn_mfma_f32_16x16x32_bf16(af[i], bfr[j], acc[i][j], 0, 0, 0);
  }

  const int rq = (lane >> 4) * 4;
  #pragma unroll
  for (int j = 0; j < 4; ++j) {
    int n = tileN + wcol + j*16 + lm;
    float bj = bias[n];
    #pragma unroll
    for (int i = 0; i < 4; ++i) {
      int mb = tileM + wrow + i*16 + rq;
      #pragma unroll
      for (int r = 0; r < 4; ++r) {
        size_t o = (size_t)(mb + r) * N + n;
        float v = acc[i][j][r] + bj;
        if (skip) v += skip[o];
        if (outF) outF[o] = v;
        else      outB[o] = __float2bfloat16(v);
      }
    }
  }
}

// ---------------- LN stats: per-sample sum/sumsq over [S,E], 8 slices per sample
__global__ __launch_bounds__(256) void ln_stats(const float* __restrict__ in,
                                                float* __restrict__ stats) {
  int samp = blockIdx.x >> 3, slice = blockIdx.x & 7;
  const float4* xp = (const float4*)(in + (size_t)samp * SE + (size_t)slice * (SE/8));
  float s = 0.f, ss = 0.f;
  for (int i = threadIdx.x; i < SE/32; i += 256) {
    float4 v = xp[i];
    s  += v.x + v.y + v.z + v.w;
    ss += v.x*v.x + v.y*v.y + v.z*v.z + v.w*v.w;
  }
  #pragma unroll
  for (int off = 32; off; off >>= 1) { s += __shfl_down(s, off); ss += __shfl_down(ss, off); }
  __shared__ float r1[4], r2[4];
  int wv = threadIdx.x >> 6;
  if ((threadIdx.x & 63) == 0) { r1[wv] = s; r2[wv] = ss; }
  __syncthreads();
  if (threadIdx.x == 0) {
    atomicAdd(&stats[samp*2],     r1[0]+r1[1]+r1[2]+r1[3]);
    atomicAdd(&stats[samp*2 + 1], r2[0]+r2[1]+r2[2]+r2[3]);
  }
}

// ---------------- LN apply
__global__ __launch_bounds__(256) void ln_apply(const float* __restrict__ in,
    const float* __restrict__ stats, const float* __restrict__ w,
    const float* __restrict__ bias, __hip_bfloat16* __restrict__ outB,
    float* __restrict__ outF) {
  int idx = blockIdx.x * 256 + threadIdx.x;      // float4 index, total 64*SE/4
  int samp = idx / (SE/4);
  int pos  = idx - samp * (SE/4);
  float S1 = stats[samp*2], S2 = stats[samp*2+1];
  float mu = S1 * (1.0f/SE);
  float var = S2 * (1.0f/SE) - mu*mu;
  float rstd = rsqrtf(var + 1e-5f);
  float4 v  = ((const float4*)in)[idx];
  float4 w4 = ((const float4*)w)[pos];
  float4 b4 = ((const float4*)bias)[pos];
  float4 r;
  r.x = (v.x - mu)*rstd*w4.x + b4.x;
  r.y = (v.y - mu)*rstd*w4.y + b4.y;
  r.z = (v.z - mu)*rstd*w4.z + b4.z;
  r.w = (v.w - mu)*rstd*w4.w + b4.w;
  if (outF) {
    ((float4*)outF)[idx] = r;
  } else {
    __hip_bfloat16* ob = outB + (size_t)idx * 4;
    ob[0] = __float2bfloat16(r.x); ob[1] = __float2bfloat16(r.y);
    ob[2] = __float2bfloat16(r.z); ob[3] = __float2bfloat16(r.w);
  }
}

// ---------------- MFMA flash attention: one block per (b,h)
// LDS: [0, 75264): K then V, row stride 384 B, XOR-swizzled 16B chunks.
//      [75264, 163456): P (normalized probs bf16), 208 rows x stride 212 elems.
__device__ __forceinline__ int kv_byte(int row, int col) {
  int c8 = col >> 3;
  int swz = (c8 & 24) | ((c8 ^ row) & 7);
  return row*384 + swz*16 + (col & 7)*2;
}

__global__ __launch_bounds__(256) void attn_mfma(const __hip_bfloat16* __restrict__ qkv,
                                                 __hip_bfloat16* __restrict__ o) {
  extern __shared__ char smem[];
  unsigned short* Pb = (unsigned short*)(smem + 75264);   // stride 212 elems
  const int bh = blockIdx.x;
  const int b = bh >> 2, h = bh & 3;
  const int tid = threadIdx.x, lane = tid & 63, wave = tid >> 6;
  const int lm = lane & 15, lq = lane >> 4;

  // ---- stage K: rows 196 x 192 bf16, swizzled
  {
    const __hip_bfloat16* kbase = qkv + (size_t)b*SS*2304 + EE + h*HD;
    for (int f = tid; f < 196*24; f += 256) {
      int row = f / 24, c8 = f % 24;
      uint4 v = *(const uint4*)(kbase + (size_t)row*2304 + c8*8);
      int swz = (c8 & 24) | ((c8 ^ row) & 7);
      *(uint4*)(smem + row*384 + swz*16) = v;
    }
  }
  __syncthreads();

  // ---- scores + softmax + P for this wave's q-tiles
  const float scale = 0.07216878364870323f;   // 1/sqrt(192)
  for (int qt = wave; qt < 13; qt += 4) {
    bf16x8 qf[6];
    const __hip_bfloat16* qrow = qkv + (size_t)(b*SS + qt*16 + lm)*2304 + h*HD + lq*8;
    #pragma unroll
    for (int c = 0; c < 6; ++c) qf[c] = *(const bf16x8*)(qrow + c*32);
    floatx4 acc[13];
    #pragma unroll
    for (int nt = 0; nt < 13; ++nt) acc[nt] = (floatx4)0.0f;
    #pragma unroll
    for (int nt = 0; nt < 13; ++nt) {
      int n = nt*16 + lm;
      #pragma unroll
      for (int c = 0; c < 6; ++c) {
        bf16x8 kf = *(const bf16x8*)(smem + kv_byte(n, c*32 + lq*8));
        acc[nt] = __builtin_amdgcn_mfma_f32_16x16x32_bf16(qf[c], kf, acc[nt], 0, 0, 0);
      }
    }
    // softmax over cols (valid cols: nt<12 all, nt==12 only lm<4)
    float rmax[4] = {-1e30f, -1e30f, -1e30f, -1e30f};
    #pragma unroll
    for (int nt = 0; nt < 13; ++nt) {
      bool valid = (nt < 12) | (lm < 4);
      #pragma unroll
      for (int r = 0; r < 4; ++r) {
        float v = acc[nt][r] * scale;
        acc[nt][r] = v;
        if (valid) rmax[r] = fmaxf(rmax[r], v);
      }
    }
    #pragma unroll
    for (int x = 1; x < 16; x <<= 1)
      #pragma unroll
      for (int r = 0; r < 4; ++r) rmax[r] = fmaxf(rmax[r], __shfl_xor(rmax[r], x));
    float rsum[4] = {0.f, 0.f, 0.f, 0.f};
    #pragma unroll
    for (int nt = 0; nt < 13; ++nt) {
      bool valid = (nt < 12) | (lm < 4);
      #pragma unroll
      for (int r = 0; r < 4; ++r) {
        float e = valid ? __expf(acc[nt][r] - rmax[r]) : 0.f;
        acc[nt][r] = e;
        rsum[r] += e;
      }
    }
    #pragma unroll
    for (int x = 1; x < 16; x <<= 1)
      #pragma unroll
      for (int r = 0; r < 4; ++r) rsum[r] += __shfl_xor(rsum[r], x);
    float inv[4];
    #pragma unroll
    for (int r = 0; r < 4; ++r) inv[r] = 1.0f / rsum[r];
    // write normalized P (bf16)
    #pragma unroll
    for (int nt = 0; nt < 13; ++nt) {
      int col = nt*16 + lm;
      #pragma unroll
      for (int r = 0; r < 4; ++r) {
        int row = qt*16 + lq*4 + r;
        if (row < SS) {
          __hip_bfloat16 hv = __float2bfloat16(acc[nt][r] * inv[r]);
          Pb[row*212 + col] = *(unsigned short*)&hv;
        }
      }
    }
  }
  __syncthreads();

  // ---- stage V over K region
  {
    const __hip_bfloat16* vbase = qkv + (size_t)b*SS*2304 + 2*EE + h*HD;
    for (int f = tid; f < 196*24; f += 256) {
      int row = f / 24, c8 = f % 24;
      uint4 v = *(const uint4*)(vbase + (size_t)row*2304 + c8*8);
      int swz = (c8 & 24) | ((c8 ^ row) & 7);
      *(uint4*)(smem + row*384 + swz*16) = v;
    }
  }
  __syncthreads();

  // ---- PV: wave owns d in [wave*48, wave*48+48), loops all 13 q-tiles
  const int d0 = wave * 48;
  union U8 { bf16x8 v; unsigned short u[8]; };
  U8 vf[3][6]; U8 vtail[3];
  #pragma unroll
  for (int nn = 0; nn < 3; ++nn) {
    int d = d0 + nn*16 + lm;
    #pragma unroll
    for (int c = 0; c < 6; ++c) {
      int sb = c*32 + lq*8;
      #pragma unroll
      for (int j = 0; j < 8; ++j)
        vf[nn][c].u[j] = *(const unsigned short*)(smem + kv_byte(sb + j, d));
    }
    #pragma unroll
    for (int j = 0; j < 8; ++j) vtail[nn].u[j] = 0;
    if (lane < 16) {
      #pragma unroll
      for (int j = 0; j < 4; ++j)
        vtail[nn].u[j] = *(const unsigned short*)(smem + kv_byte(192 + j, d0 + nn*16 + lane));
    }
  }

  for (int qt = 0; qt < 13; ++qt) {
    floatx4 O[3];
    #pragma unroll
    for (int nn = 0; nn < 3; ++nn) O[nn] = (floatx4)0.0f;
    #pragma unroll
    for (int c = 0; c < 6; ++c) {
      int e0 = (qt*16 + lm)*212 + c*32 + lq*8;
      bf16x4 lo = *(const bf16x4*)(Pb + e0);
      bf16x4 hi = *(const bf16x4*)(Pb + e0 + 4);
      bf16x8 pf = __builtin_shufflevector(lo, hi, 0, 1, 2, 3, 4, 5, 6, 7);
      #pragma unroll
      for (int nn = 0; nn < 3; ++nn)
        O[nn] = __builtin_amdgcn_mfma_f32_16x16x32_bf16(pf, vf[nn][c].v, O[nn], 0, 0, 0);
    }
    // tail: s = 192..195
    {
      U8 pt;
      #pragma unroll
      for (int j = 0; j < 8; ++j) pt.u[j] = 0;
      if (lane < 16) {
        #pragma unroll
        for (int j = 0; j < 4; ++j) pt.u[j] = Pb[(qt*16 + lane)*212 + 192 + j];
      }
      #pragma unroll
      for (int nn = 0; nn < 3; ++nn)
        O[nn] = __builtin_amdgcn_mfma_f32_16x16x32_bf16(pt.v, vtail[nn].v, O[nn], 0, 0, 0);
    }
    #pragma unroll
    for (int nn = 0; nn < 3; ++nn) {
      #pragma unroll
      for (int r = 0; r < 4; ++r) {
        int q = qt*16 + lq*4 + r;
        if (q < SS)
          o[(size_t)(b*SS + q)*EE + h*HD + d0 + nn*16 + lm] = __float2bfloat16(O[nn][r]);
      }
    }
  }
}

extern "C" void kernel_launch(void* const* d_in, const int* in_sizes, int n_in,
                              void* d_out, int out_size, void* d_ws, size_t ws_size,
                              hipStream_t stream) {
  const float* x      = (const float*)d_in[0];
  const float* conv_w = (const float*)d_in[1];
  const float* conv_b = (const float*)d_in[2];
  const float* wq = (const float*)d_in[3];
  const float* bq = (const float*)d_in[4];
  const float* wk = (const float*)d_in[5];
  const float* bk = (const float*)d_in[6];
  const float* wv = (const float*)d_in[7];
  const float* bv = (const float*)d_in[8];
  const float* wo = (const float*)d_in[9];
  const float* bo = (const float*)d_in[10];
  const float* ln1w = (const float*)d_in[11];
  const float* ln1b = (const float*)d_in[12];
  const float* ln2w = (const float*)d_in[13];
  const float* ln2b = (const float*)d_in[14];
  float* out = (float*)d_out;

  char* ws = (char*)d_ws;
  __hip_bfloat16* patches = (__hip_bfloat16*)(ws);                // 19267584 B
  __hip_bfloat16* cw_b    = (__hip_bfloat16*)(ws + 19267584);     //  1179648
  __hip_bfloat16* qkvw_b  = (__hip_bfloat16*)(ws + 20447232);     //  3538944
  __hip_bfloat16* wo_b    = (__hip_bfloat16*)(ws + 23986176);     //  1179648
  float*          qkv_b   = (float*)         (ws + 25165824);     //     9216
  float*          emb     = (float*)         (ws + 25175040);     // 38535168
  __hip_bfloat16* hbuf    = (__hip_bfloat16*)(ws + 63710208);     // 19267584
  __hip_bfloat16* qkv     = (__hip_bfloat16*)(ws + 82977792);     // 57802752
  __hip_bfloat16* obuf    = (__hip_bfloat16*)(ws + 140780544);    // 19267584
  float*          stats   = (float*)ws;  // reuses patches region after emb GEMM

  convert_weights<<<2304, 256, 0, stream>>>(conv_w, wq, wk, wv, wo, bq, bk, bv,
                                            cw_b, qkvw_b, wo_b, qkv_b);
  patch_kernel<<<MM*EE/256, 256, 0, stream>>>(x, patches);
  gemm_bt<<<dim3(6, 98), 256, 0, stream>>>(patches, cw_b, conv_b, nullptr, emb, nullptr,
                                           MM, EE, EE);
  // patches now dead; carve LN stats buffers there
  hipMemsetAsync(stats, 0, 1024, stream);
  ln_stats<<<BB*8, 256, 0, stream>>>(emb, stats);
  ln_apply<<<BB*SE/4/256, 256, 0, stream>>>(emb, stats, ln1w, ln1b, hbuf, nullptr);
  gemm_bt<<<dim3(18, 98), 256, 0, stream>>>(hbuf, qkvw_b, qkv_b, nullptr, nullptr, qkv,
                                            MM, 3*EE, EE);
  hipFuncSetAttribute((const void*)attn_mfma,
                      hipFuncAttributeMaxDynamicSharedMemorySize, 163456);
  attn_mfma<<<BB*HH, 256, 163456, stream>>>(qkv, obuf);
  gemm_bt<<<dim3(6, 98), 256, 0, stream>>>(obuf, wo_b, bo, emb, out, nullptr,
                                           MM, EE, EE);
  ln_stats<<<BB*8, 256, 0, stream>>>(out, stats + 128);
  ln_apply<<<BB*SE/4/256, 256, 0, stream>>>(out, stats + 128, ln2w, ln2b, nullptr, out);
}

// Round 3
// 381.026 us; speedup vs baseline: 3.1874x; 1.0115x over previous
//
#include <hip/hip_runtime.h>
#include <hip/hip_bf16.h>

#define GRID14 14
#define SS 196
#define EE 768
#define HH 4
#define HD 192
#define BB 64
#define MM (BB*SS)       // 12544
#define SE (SS*EE)       // 150528

typedef __bf16 bf16x8 __attribute__((ext_vector_type(8)));
typedef __bf16 bf16x4 __attribute__((ext_vector_type(4)));
typedef float floatx4 __attribute__((ext_vector_type(4)));

__device__ __forceinline__ void glds16(const void* g, void* l) {
  __builtin_amdgcn_global_load_lds(
      (const __attribute__((address_space(1))) unsigned int*)g,
      (__attribute__((address_space(3))) unsigned int*)l, 16, 0, 0);
}

// ---------------- patch extraction: x[64,3,224,224] f32 -> patches[12544,768] bf16
__global__ __launch_bounds__(256) void patch_kernel(const float* __restrict__ x,
                                                    __hip_bfloat16* __restrict__ p) {
  int idx = blockIdx.x * 256 + threadIdx.x;   // < 12544*768
  int k = idx % EE;
  int m = idx / EE;
  int b = m / SS, s = m % SS;
  int gy = s / GRID14, gx = s % GRID14;
  int c = k >> 8, rem = k & 255, py = rem >> 4, px = rem & 15;
  size_t xi = ((size_t)(b*3 + c)*224 + gy*16 + py)*224 + gx*16 + px;
  p[idx] = __float2bfloat16(x[xi]);
}

// ---------------- weight conversion + QKV weight/bias concat
__global__ __launch_bounds__(256) void convert_weights(
    const float* __restrict__ cw, const float* __restrict__ wq,
    const float* __restrict__ wk, const float* __restrict__ wv,
    const float* __restrict__ wo, const float* __restrict__ bq,
    const float* __restrict__ bk, const float* __restrict__ bv,
    __hip_bfloat16* __restrict__ cw_b, __hip_bfloat16* __restrict__ qkvw_b,
    __hip_bfloat16* __restrict__ wo_b, float* __restrict__ qkv_bias) {
  int i = blockIdx.x * 256 + threadIdx.x;
  const int WN = EE * EE;
  if (i < WN) {
    cw_b[i] = __float2bfloat16(cw[i]);
    wo_b[i] = __float2bfloat16(wo[i]);
    qkvw_b[i]        = __float2bfloat16(wq[i]);
    qkvw_b[WN + i]   = __float2bfloat16(wk[i]);
    qkvw_b[2*WN + i] = __float2bfloat16(wv[i]);
  }
  if (i < EE) { qkv_bias[i] = bq[i]; qkv_bias[EE+i] = bk[i]; qkv_bias[2*EE+i] = bv[i]; }
}

// ---------------- bf16 MFMA GEMM: out[M,N] = A[M,K] @ W[N,K]^T + bias (+skip)
// 128x128 tile, BK=32, global_load_lds width-16 staging, XOR-swizzled LDS.
// LDS chunk layout: As[row*32 + cp*8] holds global chunk c = cp ^ ((row>>1)&3).
__global__ __launch_bounds__(256, 3) void gemm_bt(
    const __hip_bfloat16* __restrict__ A, const __hip_bfloat16* __restrict__ W,
    const float* __restrict__ bias, const float* __restrict__ skip,
    float* __restrict__ outF, __hip_bfloat16* __restrict__ outB,
    int M, int N, int K) {
  __shared__ __align__(16) unsigned short As[128*32];
  __shared__ __align__(16) unsigned short Bs[128*32];
  const int tid  = threadIdx.x;
  const int lane = tid & 63;
  const int wave = tid >> 6;
  const int wrow = (wave >> 1) * 64;
  const int wcol = (wave & 1) * 64;
  const int tileM = blockIdx.y * 128;
  const int tileN = blockIdx.x * 128;
  const int lm = lane & 15;
  const int lq = lane >> 4;

  // staging: thread t covers chunk t (rows 0..63) and chunk 256+t (rows 64..127)
  const int r0 = tid >> 2;
  const int c0 = (tid & 3) ^ ((r0 >> 1) & 3);   // swizzled source chunk
  const __hip_bfloat16* a0p = A + (size_t)(tileM + r0) * K + c0 * 8;
  const __hip_bfloat16* a1p = A + (size_t)(tileM + 64 + r0) * K + c0 * 8;
  const __hip_bfloat16* b0p = W + (size_t)(tileN + r0) * K + c0 * 8;
  const __hip_bfloat16* b1p = W + (size_t)(tileN + 64 + r0) * K + c0 * 8;
  unsigned short* as0 = As + tid * 8;
  unsigned short* as1 = As + 2048 + tid * 8;
  unsigned short* bs0 = Bs + tid * 8;
  unsigned short* bs1 = Bs + 2048 + tid * 8;

  // fragment read chunk (hoistable: (row>>1)&3 == (lm>>1)&3 for 16-aligned bases)
  const int fc = (lq ^ ((lm >> 1) & 3)) * 8;

  floatx4 acc[4][4];
  #pragma unroll
  for (int i = 0; i < 4; ++i)
    #pragma unroll
    for (int j = 0; j < 4; ++j) acc[i][j] = (floatx4)0.0f;

  for (int k0 = 0; k0 < K; k0 += 32) {
    __syncthreads();
    glds16(a0p + k0, as0);
    glds16(a1p + k0, as1);
    glds16(b0p + k0, bs0);
    glds16(b1p + k0, bs1);
    __syncthreads();
    bf16x8 af[4], bfr[4];
    #pragma unroll
    for (int i = 0; i < 4; ++i) af[i]  = *(const bf16x8*)&As[(wrow + i*16 + lm)*32 + fc];
    #pragma unroll
    for (int j = 0; j < 4; ++j) bfr[j] = *(const bf16x8*)&Bs[(wcol + j*16 + lm)*32 + fc];
    #pragma unroll
    for (int i = 0; i < 4; ++i)
      #pragma unroll
      for (int j = 0; j < 4; ++j)
        acc[i][j] = __builtin_amdgcn_mfma_f32_16x16x32_bf16(af[i], bfr[j], acc[i][j], 0, 0, 0);
  }

  const int rq = lq * 4;
  #pragma unroll
  for (int j = 0; j < 4; ++j) {
    int n = tileN + wcol + j*16 + lm;
    float bj = bias[n];
    #pragma unroll
    for (int i = 0; i < 4; ++i) {
      int mb = tileM + wrow + i*16 + rq;
      #pragma unroll
      for (int r = 0; r < 4; ++r) {
        size_t o = (size_t)(mb + r) * N + n;
        float v = acc[i][j][r] + bj;
        if (skip) v += skip[o];
        if (outF) outF[o] = v;
        else      outB[o] = __float2bfloat16(v);
      }
    }
  }
}

// ---------------- LN stats: per-sample sum/sumsq over [S,E], 8 slices per sample
__global__ __launch_bounds__(256) void ln_stats(const float* __restrict__ in,
                                                float* __restrict__ stats) {
  int samp = blockIdx.x >> 3, slice = blockIdx.x & 7;
  const float4* xp = (const float4*)(in + (size_t)samp * SE + (size_t)slice * (SE/8));
  float s = 0.f, ss = 0.f;
  for (int i = threadIdx.x; i < SE/32; i += 256) {
    float4 v = xp[i];
    s  += v.x + v.y + v.z + v.w;
    ss += v.x*v.x + v.y*v.y + v.z*v.z + v.w*v.w;
  }
  #pragma unroll
  for (int off = 32; off; off >>= 1) { s += __shfl_down(s, off); ss += __shfl_down(ss, off); }
  __shared__ float r1[4], r2[4];
  int wv = threadIdx.x >> 6;
  if ((threadIdx.x & 63) == 0) { r1[wv] = s; r2[wv] = ss; }
  __syncthreads();
  if (threadIdx.x == 0) {
    atomicAdd(&stats[samp*2],     r1[0]+r1[1]+r1[2]+r1[3]);
    atomicAdd(&stats[samp*2 + 1], r2[0]+r2[1]+r2[2]+r2[3]);
  }
}

// ---------------- LN apply
__global__ __launch_bounds__(256) void ln_apply(const float* __restrict__ in,
    const float* __restrict__ stats, const float* __restrict__ w,
    const float* __restrict__ bias, __hip_bfloat16* __restrict__ outB,
    float* __restrict__ outF) {
  int idx = blockIdx.x * 256 + threadIdx.x;      // float4 index, total 64*SE/4
  int samp = idx / (SE/4);
  int pos  = idx - samp * (SE/4);
  float S1 = stats[samp*2], S2 = stats[samp*2+1];
  float mu = S1 * (1.0f/SE);
  float var = S2 * (1.0f/SE) - mu*mu;
  float rstd = rsqrtf(var + 1e-5f);
  float4 v  = ((const float4*)in)[idx];
  float4 w4 = ((const float4*)w)[pos];
  float4 b4 = ((const float4*)bias)[pos];
  float4 r;
  r.x = (v.x - mu)*rstd*w4.x + b4.x;
  r.y = (v.y - mu)*rstd*w4.y + b4.y;
  r.z = (v.z - mu)*rstd*w4.z + b4.z;
  r.w = (v.w - mu)*rstd*w4.w + b4.w;
  if (outF) {
    ((float4*)outF)[idx] = r;
  } else {
    __hip_bfloat16* ob = outB + (size_t)idx * 4;
    ob[0] = __float2bfloat16(r.x); ob[1] = __float2bfloat16(r.y);
    ob[2] = __float2bfloat16(r.z); ob[3] = __float2bfloat16(r.w);
  }
}

// ---------------- MFMA flash attention: one block per (b,h)
__device__ __forceinline__ int kv_byte(int row, int col) {
  int c8 = col >> 3;
  int swz = (c8 & 24) | ((c8 ^ row) & 7);
  return row*384 + swz*16 + (col & 7)*2;
}

__global__ __launch_bounds__(256) void attn_mfma(const __hip_bfloat16* __restrict__ qkv,
                                                 __hip_bfloat16* __restrict__ o) {
  extern __shared__ char smem[];
  unsigned short* Pb = (unsigned short*)(smem + 75264);   // stride 212 elems
  const int bh = blockIdx.x;
  const int b = bh >> 2, h = bh & 3;
  const int tid = threadIdx.x, lane = tid & 63, wave = tid >> 6;
  const int lm = lane & 15, lq = lane >> 4;

  {
    const __hip_bfloat16* kbase = qkv + (size_t)b*SS*2304 + EE + h*HD;
    for (int f = tid; f < 196*24; f += 256) {
      int row = f / 24, c8 = f % 24;
      uint4 v = *(const uint4*)(kbase + (size_t)row*2304 + c8*8);
      int swz = (c8 & 24) | ((c8 ^ row) & 7);
      *(uint4*)(smem + row*384 + swz*16) = v;
    }
  }
  __syncthreads();

  const float scale = 0.07216878364870323f;   // 1/sqrt(192)
  for (int qt = wave; qt < 13; qt += 4) {
    bf16x8 qf[6];
    const __hip_bfloat16* qrow = qkv + (size_t)(b*SS + qt*16 + lm)*2304 + h*HD + lq*8;
    #pragma unroll
    for (int c = 0; c < 6; ++c) qf[c] = *(const bf16x8*)(qrow + c*32);
    floatx4 acc[13];
    #pragma unroll
    for (int nt = 0; nt < 13; ++nt) acc[nt] = (floatx4)0.0f;
    #pragma unroll
    for (int nt = 0; nt < 13; ++nt) {
      int n = nt*16 + lm;
      #pragma unroll
      for (int c = 0; c < 6; ++c) {
        bf16x8 kf = *(const bf16x8*)(smem + kv_byte(n, c*32 + lq*8));
        acc[nt] = __builtin_amdgcn_mfma_f32_16x16x32_bf16(qf[c], kf, acc[nt], 0, 0, 0);
      }
    }
    float rmax[4] = {-1e30f, -1e30f, -1e30f, -1e30f};
    #pragma unroll
    for (int nt = 0; nt < 13; ++nt) {
      bool valid = (nt < 12) | (lm < 4);
      #pragma unroll
      for (int r = 0; r < 4; ++r) {
        float v = acc[nt][r] * scale;
        acc[nt][r] = v;
        if (valid) rmax[r] = fmaxf(rmax[r], v);
      }
    }
    #pragma unroll
    for (int x = 1; x < 16; x <<= 1)
      #pragma unroll
      for (int r = 0; r < 4; ++r) rmax[r] = fmaxf(rmax[r], __shfl_xor(rmax[r], x));
    float rsum[4] = {0.f, 0.f, 0.f, 0.f};
    #pragma unroll
    for (int nt = 0; nt < 13; ++nt) {
      bool valid = (nt < 12) | (lm < 4);
      #pragma unroll
      for (int r = 0; r < 4; ++r) {
        float e = valid ? __expf(acc[nt][r] - rmax[r]) : 0.f;
        acc[nt][r] = e;
        rsum[r] += e;
      }
    }
    #pragma unroll
    for (int x = 1; x < 16; x <<= 1)
      #pragma unroll
      for (int r = 0; r < 4; ++r) rsum[r] += __shfl_xor(rsum[r], x);
    float inv[4];
    #pragma unroll
    for (int r = 0; r < 4; ++r) inv[r] = 1.0f / rsum[r];
    #pragma unroll
    for (int nt = 0; nt < 13; ++nt) {
      int col = nt*16 + lm;
      #pragma unroll
      for (int r = 0; r < 4; ++r) {
        int row = qt*16 + lq*4 + r;
        if (row < SS) {
          __hip_bfloat16 hv = __float2bfloat16(acc[nt][r] * inv[r]);
          Pb[row*212 + col] = *(unsigned short*)&hv;
        }
      }
    }
  }
  __syncthreads();

  {
    const __hip_bfloat16* vbase = qkv + (size_t)b*SS*2304 + 2*EE + h*HD;
    for (int f = tid; f < 196*24; f += 256) {
      int row = f / 24, c8 = f % 24;
      uint4 v = *(const uint4*)(vbase + (size_t)row*2304 + c8*8);
      int swz = (c8 & 24) | ((c8 ^ row) & 7);
      *(uint4*)(smem + row*384 + swz*16) = v;
    }
  }
  __syncthreads();

  const int d0 = wave * 48;
  union U8 { bf16x8 v; unsigned short u[8]; };
  U8 vf[3][6]; U8 vtail[3];
  #pragma unroll
  for (int nn = 0; nn < 3; ++nn) {
    int d = d0 + nn*16 + lm;
    #pragma unroll
    for (int c = 0; c < 6; ++c) {
      int sb = c*32 + lq*8;
      #pragma unroll
      for (int j = 0; j < 8; ++j)
        vf[nn][c].u[j] = *(const unsigned short*)(smem + kv_byte(sb + j, d));
    }
    #pragma unroll
    for (int j = 0; j < 8; ++j) vtail[nn].u[j] = 0;
    if (lane < 16) {
      #pragma unroll
      for (int j = 0; j < 4; ++j)
        vtail[nn].u[j] = *(const unsigned short*)(smem + kv_byte(192 + j, d0 + nn*16 + lane));
    }
  }

  for (int qt = 0; qt < 13; ++qt) {
    floatx4 O[3];
    #pragma unroll
    for (int nn = 0; nn < 3; ++nn) O[nn] = (floatx4)0.0f;
    #pragma unroll
    for (int c = 0; c < 6; ++c) {
      int e0 = (qt*16 + lm)*212 + c*32 + lq*8;
      bf16x4 lo = *(const bf16x4*)(Pb + e0);
      bf16x4 hi = *(const bf16x4*)(Pb + e0 + 4);
      bf16x8 pf = __builtin_shufflevector(lo, hi, 0, 1, 2, 3, 4, 5, 6, 7);
      #pragma unroll
      for (int nn = 0; nn < 3; ++nn)
        O[nn] = __builtin_amdgcn_mfma_f32_16x16x32_bf16(pf, vf[nn][c].v, O[nn], 0, 0, 0);
    }
    {
      U8 pt;
      #pragma unroll
      for (int j = 0; j < 8; ++j) pt.u[j] = 0;
      if (lane < 16) {
        #pragma unroll
        for (int j = 0; j < 4; ++j) pt.u[j] = Pb[(qt*16 + lane)*212 + 192 + j];
      }
      #pragma unroll
      for (int nn = 0; nn < 3; ++nn)
        O[nn] = __builtin_amdgcn_mfma_f32_16x16x32_bf16(pt.v, vtail[nn].v, O[nn], 0, 0, 0);
    }
    #pragma unroll
    for (int nn = 0; nn < 3; ++nn) {
      #pragma unroll
      for (int r = 0; r < 4; ++r) {
        int q = qt*16 + lq*4 + r;
        if (q < SS)
          o[(size_t)(b*SS + q)*EE + h*HD + d0 + nn*16 + lm] = __float2bfloat16(O[nn][r]);
      }
    }
  }
}

extern "C" void kernel_launch(void* const* d_in, const int* in_sizes, int n_in,
                              void* d_out, int out_size, void* d_ws, size_t ws_size,
                              hipStream_t stream) {
  const float* x      = (const float*)d_in[0];
  const float* conv_w = (const float*)d_in[1];
  const float* conv_b = (const float*)d_in[2];
  const float* wq = (const float*)d_in[3];
  const float* bq = (const float*)d_in[4];
  const float* wk = (const float*)d_in[5];
  const float* bk = (const float*)d_in[6];
  const float* wv = (const float*)d_in[7];
  const float* bv = (const float*)d_in[8];
  const float* wo = (const float*)d_in[9];
  const float* bo = (const float*)d_in[10];
  const float* ln1w = (const float*)d_in[11];
  const float* ln1b = (const float*)d_in[12];
  const float* ln2w = (const float*)d_in[13];
  const float* ln2b = (const float*)d_in[14];
  float* out = (float*)d_out;

  char* ws = (char*)d_ws;
  __hip_bfloat16* patches = (__hip_bfloat16*)(ws);                // 19267584 B
  __hip_bfloat16* cw_b    = (__hip_bfloat16*)(ws + 19267584);     //  1179648
  __hip_bfloat16* qkvw_b  = (__hip_bfloat16*)(ws + 20447232);     //  3538944
  __hip_bfloat16* wo_b    = (__hip_bfloat16*)(ws + 23986176);     //  1179648
  float*          qkv_b   = (float*)         (ws + 25165824);     //     9216
  float*          emb     = (float*)         (ws + 25175040);     // 38535168
  __hip_bfloat16* hbuf    = (__hip_bfloat16*)(ws + 63710208);     // 19267584
  __hip_bfloat16* qkv     = (__hip_bfloat16*)(ws + 82977792);     // 57802752
  __hip_bfloat16* obuf    = (__hip_bfloat16*)(ws + 140780544);    // 19267584
  float*          stats   = (float*)ws;  // reuses patches region after emb GEMM

  convert_weights<<<2304, 256, 0, stream>>>(conv_w, wq, wk, wv, wo, bq, bk, bv,
                                            cw_b, qkvw_b, wo_b, qkv_b);
  patch_kernel<<<MM*EE/256, 256, 0, stream>>>(x, patches);
  gemm_bt<<<dim3(6, 98), 256, 0, stream>>>(patches, cw_b, conv_b, nullptr, emb, nullptr,
                                           MM, EE, EE);
  hipMemsetAsync(stats, 0, 1024, stream);
  ln_stats<<<BB*8, 256, 0, stream>>>(emb, stats);
  ln_apply<<<BB*SE/4/256, 256, 0, stream>>>(emb, stats, ln1w, ln1b, hbuf, nullptr);
  gemm_bt<<<dim3(18, 98), 256, 0, stream>>>(hbuf, qkvw_b, qkv_b, nullptr, nullptr, qkv,
                                            MM, 3*EE, EE);
  hipFuncSetAttribute((const void*)attn_mfma,
                      hipFuncAttributeMaxDynamicSharedMemorySize, 163456);
  attn_mfma<<<BB*HH, 256, 163456, stream>>>(qkv, obuf);
  gemm_bt<<<dim3(6, 98), 256, 0, stream>>>(obuf, wo_b, bo, emb, out, nullptr,
                                           MM, EE, EE);
  ln_stats<<<BB*8, 256, 0, stream>>>(out, stats + 128);
  ln_apply<<<BB*SE/4/256, 256, 0, stream>>>(out, stats + 128, ln2w, ln2b, nullptr, out);
}

// Round 4
// 371.584 us; speedup vs baseline: 3.2684x; 1.0254x over previous
//
#include <hip/hip_runtime.h>
#include <hip/hip_bf16.h>

#define GRID14 14
#define SS 196
#define EE 768
#define HH 4
#define HD 192
#define BB 64
#define MM (BB*SS)       // 12544
#define SE (SS*EE)       // 150528

typedef __bf16 bf16x8 __attribute__((ext_vector_type(8)));
typedef __bf16 bf16x4 __attribute__((ext_vector_type(4)));
typedef float floatx4 __attribute__((ext_vector_type(4)));

__device__ __forceinline__ void glds16(const void* g, void* l) {
  __builtin_amdgcn_global_load_lds(
      (const __attribute__((address_space(1))) unsigned int*)g,
      (__attribute__((address_space(3))) unsigned int*)l, 16, 0, 0);
}

// ---------------- patch extraction: x[64,3,224,224] f32 -> patches[12544,768] bf16
__global__ __launch_bounds__(256) void patch_kernel(const float* __restrict__ x,
                                                    __hip_bfloat16* __restrict__ p) {
  int idx = blockIdx.x * 256 + threadIdx.x;   // < 12544*768
  int k = idx % EE;
  int m = idx / EE;
  int b = m / SS, s = m % SS;
  int gy = s / GRID14, gx = s % GRID14;
  int c = k >> 8, rem = k & 255, py = rem >> 4, px = rem & 15;
  size_t xi = ((size_t)(b*3 + c)*224 + gy*16 + py)*224 + gx*16 + px;
  p[idx] = __float2bfloat16(x[xi]);
}

// ---------------- weight conversion + QKV weight/bias concat
__global__ __launch_bounds__(256) void convert_weights(
    const float* __restrict__ cw, const float* __restrict__ wq,
    const float* __restrict__ wk, const float* __restrict__ wv,
    const float* __restrict__ wo, const float* __restrict__ bq,
    const float* __restrict__ bk, const float* __restrict__ bv,
    __hip_bfloat16* __restrict__ cw_b, __hip_bfloat16* __restrict__ qkvw_b,
    __hip_bfloat16* __restrict__ wo_b, float* __restrict__ qkv_bias) {
  int i = blockIdx.x * 256 + threadIdx.x;
  const int WN = EE * EE;
  if (i < WN) {
    cw_b[i] = __float2bfloat16(cw[i]);
    wo_b[i] = __float2bfloat16(wo[i]);
    qkvw_b[i]        = __float2bfloat16(wq[i]);
    qkvw_b[WN + i]   = __float2bfloat16(wk[i]);
    qkvw_b[2*WN + i] = __float2bfloat16(wv[i]);
  }
  if (i < EE) { qkv_bias[i] = bq[i]; qkv_bias[EE+i] = bk[i]; qkv_bias[2*EE+i] = bv[i]; }
}

// ---------------- bf16 MFMA GEMM: out[M,N] = A[M,K] @ W[N,K]^T + bias (+skip)
// 128x128 tile, BK=32, global_load_lds width-16, XOR-swizzled LDS.
// 1-D grid with XCD-aware remap: all NBX blocks of one tileM land on one XCD.
// Optional fused LayerNorm stats (sum/sumsq per 196-row sample) via atomics.
__global__ __launch_bounds__(256, 3) void gemm_bt(
    const __hip_bfloat16* __restrict__ A, const __hip_bfloat16* __restrict__ W,
    const float* __restrict__ bias, const float* __restrict__ skip,
    float* __restrict__ outF, __hip_bfloat16* __restrict__ outB,
    float* __restrict__ stats, int N, int K, int NBX) {
  __shared__ __align__(16) unsigned short As[128*32];
  __shared__ __align__(16) unsigned short Bs[128*32];
  const int NBY = MM >> 7;   // 98
  int l = blockIdx.x;
  int g = l >> 3;
  int bx = g % NBX;
  int by = (l & 7) + 8 * (g / NBX);
  if (by >= NBY) return;
  const int tileM = by * 128;
  const int tileN = bx * 128;
  const int tid  = threadIdx.x;
  const int lane = tid & 63;
  const int wave = tid >> 6;
  const int wrow = (wave >> 1) * 64;
  const int wcol = (wave & 1) * 64;
  const int lm = lane & 15;
  const int lq = lane >> 4;

  const int r0 = tid >> 2;
  const int c0 = (tid & 3) ^ ((r0 >> 1) & 3);   // swizzled source chunk
  const __hip_bfloat16* a0p = A + (size_t)(tileM + r0) * K + c0 * 8;
  const __hip_bfloat16* a1p = A + (size_t)(tileM + 64 + r0) * K + c0 * 8;
  const __hip_bfloat16* b0p = W + (size_t)(tileN + r0) * K + c0 * 8;
  const __hip_bfloat16* b1p = W + (size_t)(tileN + 64 + r0) * K + c0 * 8;
  unsigned short* as0 = As + tid * 8;
  unsigned short* as1 = As + 2048 + tid * 8;
  unsigned short* bs0 = Bs + tid * 8;
  unsigned short* bs1 = Bs + 2048 + tid * 8;

  const int fc = (lq ^ ((lm >> 1) & 3)) * 8;

  floatx4 acc[4][4];
  #pragma unroll
  for (int i = 0; i < 4; ++i)
    #pragma unroll
    for (int j = 0; j < 4; ++j) acc[i][j] = (floatx4)0.0f;

  for (int k0 = 0; k0 < K; k0 += 32) {
    __syncthreads();
    glds16(a0p + k0, as0);
    glds16(a1p + k0, as1);
    glds16(b0p + k0, bs0);
    glds16(b1p + k0, bs1);
    __syncthreads();
    bf16x8 af[4], bfr[4];
    #pragma unroll
    for (int i = 0; i < 4; ++i) af[i]  = *(const bf16x8*)&As[(wrow + i*16 + lm)*32 + fc];
    #pragma unroll
    for (int j = 0; j < 4; ++j) bfr[j] = *(const bf16x8*)&Bs[(wcol + j*16 + lm)*32 + fc];
    #pragma unroll
    for (int i = 0; i < 4; ++i)
      #pragma unroll
      for (int j = 0; j < 4; ++j)
        acc[i][j] = __builtin_amdgcn_mfma_f32_16x16x32_bf16(af[i], bfr[j], acc[i][j], 0, 0, 0);
  }

  const int rq = lq * 4;
  const int sA = tileM / SS;                 // first sample this tile touches
  const int boundary = (sA + 1) * SS;        // first row of next sample
  float p0s = 0.f, p0q = 0.f, p1s = 0.f, p1q = 0.f;
  #pragma unroll
  for (int j = 0; j < 4; ++j) {
    int n = tileN + wcol + j*16 + lm;
    float bj = bias[n];
    #pragma unroll
    for (int i = 0; i < 4; ++i) {
      int mb = tileM + wrow + i*16 + rq;
      #pragma unroll
      for (int r = 0; r < 4; ++r) {
        int row = mb + r;
        size_t o = (size_t)row * N + n;
        float v = acc[i][j][r] + bj;
        if (skip) v += skip[o];
        if (outF) outF[o] = v;
        else      outB[o] = __float2bfloat16(v);
        if (stats) {
          if (row < boundary) { p0s += v; p0q += v*v; }
          else                { p1s += v; p1q += v*v; }
        }
      }
    }
  }
  if (stats) {
    #pragma unroll
    for (int off = 32; off; off >>= 1) {
      p0s += __shfl_down(p0s, off); p0q += __shfl_down(p0q, off);
      p1s += __shfl_down(p1s, off); p1q += __shfl_down(p1q, off);
    }
    __syncthreads();                 // done with As; reuse as scratch
    float* red = (float*)As;
    if (lane == 0) {
      red[wave*4+0] = p0s; red[wave*4+1] = p0q;
      red[wave*4+2] = p1s; red[wave*4+3] = p1q;
    }
    __syncthreads();
    if (tid == 0) {
      float t0 = red[0]+red[4]+red[8]+red[12];
      float t1 = red[1]+red[5]+red[9]+red[13];
      float t2 = red[2]+red[6]+red[10]+red[14];
      float t3 = red[3]+red[7]+red[11]+red[15];
      atomicAdd(&stats[2*sA],   t0);
      atomicAdd(&stats[2*sA+1], t1);
      if (boundary <= tileM + 127 && sA + 1 < BB) {
        atomicAdd(&stats[2*sA+2], t2);
        atomicAdd(&stats[2*sA+3], t3);
      }
    }
  }
}

// ---------------- LN apply (stats = per-sample {sum, sumsq})
__global__ __launch_bounds__(256) void ln_apply(const float* __restrict__ in,
    const float* __restrict__ stats, const float* __restrict__ w,
    const float* __restrict__ bias, __hip_bfloat16* __restrict__ outB,
    float* __restrict__ outF) {
  int idx = blockIdx.x * 256 + threadIdx.x;      // float4 index, total 64*SE/4
  int samp = idx / (SE/4);
  int pos  = idx - samp * (SE/4);
  float S1 = stats[samp*2], S2 = stats[samp*2+1];
  float mu = S1 * (1.0f/SE);
  float var = S2 * (1.0f/SE) - mu*mu;
  float rstd = rsqrtf(var + 1e-5f);
  float4 v  = ((const float4*)in)[idx];
  float4 w4 = ((const float4*)w)[pos];
  float4 b4 = ((const float4*)bias)[pos];
  float4 r;
  r.x = (v.x - mu)*rstd*w4.x + b4.x;
  r.y = (v.y - mu)*rstd*w4.y + b4.y;
  r.z = (v.z - mu)*rstd*w4.z + b4.z;
  r.w = (v.w - mu)*rstd*w4.w + b4.w;
  if (outF) {
    ((float4*)outF)[idx] = r;
  } else {
    __hip_bfloat16 h0 = __float2bfloat16(r.x), h1 = __float2bfloat16(r.y);
    __hip_bfloat16 h2 = __float2bfloat16(r.z), h3 = __float2bfloat16(r.w);
    ushort4 us;
    us.x = *(unsigned short*)&h0; us.y = *(unsigned short*)&h1;
    us.z = *(unsigned short*)&h2; us.w = *(unsigned short*)&h3;
    *(ushort4*)(outB + (size_t)idx * 4) = us;
  }
}

// ---------------- MFMA flash attention: one block per (b,h)
__device__ __forceinline__ int kv_byte(int row, int col) {
  int c8 = col >> 3;
  int swz = (c8 & 24) | ((c8 ^ row) & 7);
  return row*384 + swz*16 + (col & 7)*2;
}

__global__ __launch_bounds__(256) void attn_mfma(const __hip_bfloat16* __restrict__ qkv,
                                                 __hip_bfloat16* __restrict__ o) {
  extern __shared__ char smem[];
  unsigned short* Pb = (unsigned short*)(smem + 75264);   // stride 212 elems
  const int bh = blockIdx.x;
  const int b = bh >> 2, h = bh & 3;
  const int tid = threadIdx.x, lane = tid & 63, wave = tid >> 6;
  const int lm = lane & 15, lq = lane >> 4;

  {
    const __hip_bfloat16* kbase = qkv + (size_t)b*SS*2304 + EE + h*HD;
    for (int f = tid; f < 196*24; f += 256) {
      int row = f / 24, c8 = f % 24;
      uint4 v = *(const uint4*)(kbase + (size_t)row*2304 + c8*8);
      int swz = (c8 & 24) | ((c8 ^ row) & 7);
      *(uint4*)(smem + row*384 + swz*16) = v;
    }
  }
  __syncthreads();

  const float scale = 0.07216878364870323f;   // 1/sqrt(192)
  for (int qt = wave; qt < 13; qt += 4) {
    bf16x8 qf[6];
    const __hip_bfloat16* qrow = qkv + (size_t)(b*SS + qt*16 + lm)*2304 + h*HD + lq*8;
    #pragma unroll
    for (int c = 0; c < 6; ++c) qf[c] = *(const bf16x8*)(qrow + c*32);
    floatx4 acc[13];
    #pragma unroll
    for (int nt = 0; nt < 13; ++nt) acc[nt] = (floatx4)0.0f;
    #pragma unroll
    for (int nt = 0; nt < 13; ++nt) {
      int n = nt*16 + lm;
      #pragma unroll
      for (int c = 0; c < 6; ++c) {
        bf16x8 kf = *(const bf16x8*)(smem + kv_byte(n, c*32 + lq*8));
        acc[nt] = __builtin_amdgcn_mfma_f32_16x16x32_bf16(qf[c], kf, acc[nt], 0, 0, 0);
      }
    }
    float rmax[4] = {-1e30f, -1e30f, -1e30f, -1e30f};
    #pragma unroll
    for (int nt = 0; nt < 13; ++nt) {
      bool valid = (nt < 12) | (lm < 4);
      #pragma unroll
      for (int r = 0; r < 4; ++r) {
        float v = acc[nt][r] * scale;
        acc[nt][r] = v;
        if (valid) rmax[r] = fmaxf(rmax[r], v);
      }
    }
    #pragma unroll
    for (int x = 1; x < 16; x <<= 1)
      #pragma unroll
      for (int r = 0; r < 4; ++r) rmax[r] = fmaxf(rmax[r], __shfl_xor(rmax[r], x));
    float rsum[4] = {0.f, 0.f, 0.f, 0.f};
    #pragma unroll
    for (int nt = 0; nt < 13; ++nt) {
      bool valid = (nt < 12) | (lm < 4);
      #pragma unroll
      for (int r = 0; r < 4; ++r) {
        float e = valid ? __expf(acc[nt][r] - rmax[r]) : 0.f;
        acc[nt][r] = e;
        rsum[r] += e;
      }
    }
    #pragma unroll
    for (int x = 1; x < 16; x <<= 1)
      #pragma unroll
      for (int r = 0; r < 4; ++r) rsum[r] += __shfl_xor(rsum[r], x);
    float inv[4];
    #pragma unroll
    for (int r = 0; r < 4; ++r) inv[r] = 1.0f / rsum[r];
    #pragma unroll
    for (int nt = 0; nt < 13; ++nt) {
      int col = nt*16 + lm;
      #pragma unroll
      for (int r = 0; r < 4; ++r) {
        int row = qt*16 + lq*4 + r;
        if (row < SS) {
          __hip_bfloat16 hv = __float2bfloat16(acc[nt][r] * inv[r]);
          Pb[row*212 + col] = *(unsigned short*)&hv;
        }
      }
    }
  }
  __syncthreads();

  {
    const __hip_bfloat16* vbase = qkv + (size_t)b*SS*2304 + 2*EE + h*HD;
    for (int f = tid; f < 196*24; f += 256) {
      int row = f / 24, c8 = f % 24;
      uint4 v = *(const uint4*)(vbase + (size_t)row*2304 + c8*8);
      int swz = (c8 & 24) | ((c8 ^ row) & 7);
      *(uint4*)(smem + row*384 + swz*16) = v;
    }
  }
  __syncthreads();

  const int d0 = wave * 48;
  union U8 { bf16x8 v; unsigned short u[8]; };
  U8 vf[3][6]; U8 vtail[3];
  #pragma unroll
  for (int nn = 0; nn < 3; ++nn) {
    int d = d0 + nn*16 + lm;
    #pragma unroll
    for (int c = 0; c < 6; ++c) {
      int sb = c*32 + lq*8;
      #pragma unroll
      for (int j = 0; j < 8; ++j)
        vf[nn][c].u[j] = *(const unsigned short*)(smem + kv_byte(sb + j, d));
    }
    #pragma unroll
    for (int j = 0; j < 8; ++j) vtail[nn].u[j] = 0;
    if (lane < 16) {
      #pragma unroll
      for (int j = 0; j < 4; ++j)
        vtail[nn].u[j] = *(const unsigned short*)(smem + kv_byte(192 + j, d0 + nn*16 + lane));
    }
  }

  for (int qt = 0; qt < 13; ++qt) {
    floatx4 O[3];
    #pragma unroll
    for (int nn = 0; nn < 3; ++nn) O[nn] = (floatx4)0.0f;
    #pragma unroll
    for (int c = 0; c < 6; ++c) {
      int e0 = (qt*16 + lm)*212 + c*32 + lq*8;
      bf16x4 lo = *(const bf16x4*)(Pb + e0);
      bf16x4 hi = *(const bf16x4*)(Pb + e0 + 4);
      bf16x8 pf = __builtin_shufflevector(lo, hi, 0, 1, 2, 3, 4, 5, 6, 7);
      #pragma unroll
      for (int nn = 0; nn < 3; ++nn)
        O[nn] = __builtin_amdgcn_mfma_f32_16x16x32_bf16(pf, vf[nn][c].v, O[nn], 0, 0, 0);
    }
    {
      U8 pt;
      #pragma unroll
      for (int j = 0; j < 8; ++j) pt.u[j] = 0;
      if (lane < 16) {
        #pragma unroll
        for (int j = 0; j < 4; ++j) pt.u[j] = Pb[(qt*16 + lane)*212 + 192 + j];
      }
      #pragma unroll
      for (int nn = 0; nn < 3; ++nn)
        O[nn] = __builtin_amdgcn_mfma_f32_16x16x32_bf16(pt.v, vtail[nn].v, O[nn], 0, 0, 0);
    }
    #pragma unroll
    for (int nn = 0; nn < 3; ++nn) {
      #pragma unroll
      for (int r = 0; r < 4; ++r) {
        int q = qt*16 + lq*4 + r;
        if (q < SS)
          o[(size_t)(b*SS + q)*EE + h*HD + d0 + nn*16 + lm] = __float2bfloat16(O[nn][r]);
      }
    }
  }
}

extern "C" void kernel_launch(void* const* d_in, const int* in_sizes, int n_in,
                              void* d_out, int out_size, void* d_ws, size_t ws_size,
                              hipStream_t stream) {
  const float* x      = (const float*)d_in[0];
  const float* conv_w = (const float*)d_in[1];
  const float* conv_b = (const float*)d_in[2];
  const float* wq = (const float*)d_in[3];
  const float* bq = (const float*)d_in[4];
  const float* wk = (const float*)d_in[5];
  const float* bk = (const float*)d_in[6];
  const float* wv = (const float*)d_in[7];
  const float* bv = (const float*)d_in[8];
  const float* wo = (const float*)d_in[9];
  const float* bo = (const float*)d_in[10];
  const float* ln1w = (const float*)d_in[11];
  const float* ln1b = (const float*)d_in[12];
  const float* ln2w = (const float*)d_in[13];
  const float* ln2b = (const float*)d_in[14];
  float* out = (float*)d_out;

  char* ws = (char*)d_ws;
  __hip_bfloat16* patches = (__hip_bfloat16*)(ws);                // 19267584 B
  __hip_bfloat16* cw_b    = (__hip_bfloat16*)(ws + 19267584);     //  1179648
  __hip_bfloat16* qkvw_b  = (__hip_bfloat16*)(ws + 20447232);     //  3538944
  __hip_bfloat16* wo_b    = (__hip_bfloat16*)(ws + 23986176);     //  1179648
  float*          qkv_b   = (float*)         (ws + 25165824);     //     9216
  float*          emb     = (float*)         (ws + 25175040);     // 38535168
  __hip_bfloat16* hbuf    = (__hip_bfloat16*)(ws + 63710208);     // 19267584
  __hip_bfloat16* qkv     = (__hip_bfloat16*)(ws + 82977792);     // 57802752
  __hip_bfloat16* obuf    = (__hip_bfloat16*)(ws + 140780544);    // 19267584
  float*          stats   = (float*)(ws + 160048128);             //     1024

  // stats[0..127] = LN1 {sum,sumsq} per sample; stats[128..255] = LN2
  hipMemsetAsync(stats, 0, 1024, stream);
  convert_weights<<<2304, 256, 0, stream>>>(conv_w, wq, wk, wv, wo, bq, bk, bv,
                                            cw_b, qkvw_b, wo_b, qkv_b);
  patch_kernel<<<MM*EE/256, 256, 0, stream>>>(x, patches);
  // emb = patches @ conv_w^T + conv_b (fp32) + fused LN1 stats
  gemm_bt<<<6*104, 256, 0, stream>>>(patches, cw_b, conv_b, nullptr, emb, nullptr,
                                     stats, EE, EE, 6);
  ln_apply<<<BB*SE/4/256, 256, 0, stream>>>(emb, stats, ln1w, ln1b, hbuf, nullptr);
  gemm_bt<<<18*104, 256, 0, stream>>>(hbuf, qkvw_b, qkv_b, nullptr, nullptr, qkv,
                                      nullptr, 3*EE, EE, 18);
  hipFuncSetAttribute((const void*)attn_mfma,
                      hipFuncAttributeMaxDynamicSharedMemorySize, 163456);
  attn_mfma<<<BB*HH, 256, 163456, stream>>>(qkv, obuf);
  // out_pre = obuf @ wo^T + bo + emb (fp32) + fused LN2 stats
  gemm_bt<<<6*104, 256, 0, stream>>>(obuf, wo_b, bo, emb, out, nullptr,
                                     stats + 128, EE, EE, 6);
  ln_apply<<<BB*SE/4/256, 256, 0, stream>>>(out, stats + 128, ln2w, ln2b, nullptr, out);
}

// Round 5
// 352.362 us; speedup vs baseline: 3.4467x; 1.0546x over previous
//
#include <hip/hip_runtime.h>
#include <hip/hip_bf16.h>

#define GRID14 14
#define SS 196
#define EE 768
#define HH 4
#define HD 192
#define BB 64
#define MM (BB*SS)       // 12544
#define SE (SS*EE)       // 150528

typedef __bf16 bf16x8 __attribute__((ext_vector_type(8)));
typedef __bf16 bf16x4 __attribute__((ext_vector_type(4)));
typedef float floatx4 __attribute__((ext_vector_type(4)));

__device__ __forceinline__ void glds16(const void* g, void* l) {
  __builtin_amdgcn_global_load_lds(
      (const __attribute__((address_space(1))) unsigned int*)g,
      (__attribute__((address_space(3))) unsigned int*)l, 16, 0, 0);
}

__device__ __forceinline__ unsigned short bfbits(float f) {
  __hip_bfloat16 h = __float2bfloat16(f);
  return *(unsigned short*)&h;
}

// convert 8 consecutive fp32 -> 8 bf16, write 16B to LDS
__device__ __forceinline__ void cvt8(const float* __restrict__ g, unsigned short* l) {
  float4 f0 = *(const float4*)g;
  float4 f1 = *(const float4*)(g + 4);
  union { uint4 q; unsigned short u[8]; } t;
  t.u[0] = bfbits(f0.x); t.u[1] = bfbits(f0.y);
  t.u[2] = bfbits(f0.z); t.u[3] = bfbits(f0.w);
  t.u[4] = bfbits(f1.x); t.u[5] = bfbits(f1.y);
  t.u[6] = bfbits(f1.z); t.u[7] = bfbits(f1.w);
  *(uint4*)l = t.q;
}

// ---------------- weight conversion + QKV weight/bias concat
__global__ __launch_bounds__(256) void convert_weights(
    const float* __restrict__ cw, const float* __restrict__ wq,
    const float* __restrict__ wk, const float* __restrict__ wv,
    const float* __restrict__ wo, const float* __restrict__ bq,
    const float* __restrict__ bk, const float* __restrict__ bv,
    __hip_bfloat16* __restrict__ cw_b, __hip_bfloat16* __restrict__ qkvw_b,
    __hip_bfloat16* __restrict__ wo_b, float* __restrict__ qkv_bias) {
  int i = blockIdx.x * 256 + threadIdx.x;
  const int WN = EE * EE;
  if (i < WN) {
    cw_b[i] = __float2bfloat16(cw[i]);
    wo_b[i] = __float2bfloat16(wo[i]);
    qkvw_b[i]        = __float2bfloat16(wq[i]);
    qkvw_b[WN + i]   = __float2bfloat16(wk[i]);
    qkvw_b[2*WN + i] = __float2bfloat16(wv[i]);
  }
  if (i < EE) { qkv_bias[i] = bq[i]; qkv_bias[EE+i] = bk[i]; qkv_bias[2*EE+i] = bv[i]; }
}

// ---------------- emb GEMM with fused patch extraction + LN1 stats
// out[M,768] = patches(x)[M,768] @ cw^T + conv_b   (fp32), stats = {sum,sumsq}/sample
__global__ __launch_bounds__(256, 3) void gemm_patch(
    const float* __restrict__ x, const __hip_bfloat16* __restrict__ W,
    const float* __restrict__ bias, float* __restrict__ outF,
    float* __restrict__ stats) {
  __shared__ __align__(16) unsigned short As[128*32];
  __shared__ __align__(16) unsigned short Bs[128*32];
  const int K = EE, N = EE;
  const int tileM = blockIdx.y * 128;
  const int tileN = blockIdx.x * 128;
  const int tid  = threadIdx.x;
  const int lane = tid & 63;
  const int wave = tid >> 6;
  const int wrow = (wave >> 1) * 64;
  const int wcol = (wave & 1) * 64;
  const int lm = lane & 15;
  const int lq = lane >> 4;

  const int r0 = tid >> 2;
  const int c0 = (tid & 3) ^ ((r0 >> 1) & 3);   // swizzled source chunk
  // patch geometry for rows tileM+r0 and tileM+64+r0
  int m0 = tileM + r0;
  int b0 = m0 / SS, s0 = m0 - b0*SS;
  int gy0 = s0 / GRID14, gx0 = s0 - gy0*GRID14;
  const float* xb0 = x + ((size_t)(b0*3)*224 + gy0*16)*224 + gx0*16;
  int m1 = m0 + 64;
  int b1 = m1 / SS, s1 = m1 - b1*SS;
  int gy1 = s1 / GRID14, gx1 = s1 - gy1*GRID14;
  const float* xb1 = x + ((size_t)(b1*3)*224 + gy1*16)*224 + gx1*16;

  const __hip_bfloat16* b0p = W + (size_t)(tileN + r0) * K + c0 * 8;
  const __hip_bfloat16* b1p = W + (size_t)(tileN + 64 + r0) * K + c0 * 8;
  unsigned short* as0 = As + tid * 8;
  unsigned short* as1 = As + 2048 + tid * 8;
  unsigned short* bs0 = Bs + tid * 8;
  unsigned short* bs1 = Bs + 2048 + tid * 8;
  const int fc = (lq ^ ((lm >> 1) & 3)) * 8;

  floatx4 acc[4][4];
  #pragma unroll
  for (int i = 0; i < 4; ++i)
    #pragma unroll
    for (int j = 0; j < 4; ++j) acc[i][j] = (floatx4)0.0f;

  for (int k0 = 0; k0 < K; k0 += 32) {
    int k = k0 + c0*8;
    int off = (k >> 8)*50176 + ((k >> 4) & 15)*224 + (k & 15);
    __syncthreads();
    cvt8(xb0 + off, as0);
    cvt8(xb1 + off, as1);
    glds16(b0p + k0, bs0);
    glds16(b1p + k0, bs1);
    __syncthreads();
    bf16x8 af[4], bfr[4];
    #pragma unroll
    for (int i = 0; i < 4; ++i) af[i]  = *(const bf16x8*)&As[(wrow + i*16 + lm)*32 + fc];
    #pragma unroll
    for (int j = 0; j < 4; ++j) bfr[j] = *(const bf16x8*)&Bs[(wcol + j*16 + lm)*32 + fc];
    #pragma unroll
    for (int i = 0; i < 4; ++i)
      #pragma unroll
      for (int j = 0; j < 4; ++j)
        acc[i][j] = __builtin_amdgcn_mfma_f32_16x16x32_bf16(af[i], bfr[j], acc[i][j], 0, 0, 0);
  }

  const int rq = lq * 4;
  const int sA = tileM / SS;
  const int boundary = (sA + 1) * SS;
  float p0s = 0.f, p0q = 0.f, p1s = 0.f, p1q = 0.f;
  #pragma unroll
  for (int j = 0; j < 4; ++j) {
    int n = tileN + wcol + j*16 + lm;
    float bj = bias[n];
    #pragma unroll
    for (int i = 0; i < 4; ++i) {
      int mb = tileM + wrow + i*16 + rq;
      #pragma unroll
      for (int r = 0; r < 4; ++r) {
        int row = mb + r;
        float v = acc[i][j][r] + bj;
        outF[(size_t)row * N + n] = v;
        if (row < boundary) { p0s += v; p0q += v*v; }
        else                { p1s += v; p1q += v*v; }
      }
    }
  }
  #pragma unroll
  for (int off = 32; off; off >>= 1) {
    p0s += __shfl_down(p0s, off); p0q += __shfl_down(p0q, off);
    p1s += __shfl_down(p1s, off); p1q += __shfl_down(p1q, off);
  }
  __syncthreads();
  float* red = (float*)As;
  if (lane == 0) {
    red[wave*4+0] = p0s; red[wave*4+1] = p0q;
    red[wave*4+2] = p1s; red[wave*4+3] = p1q;
  }
  __syncthreads();
  if (tid == 0) {
    atomicAdd(&stats[2*sA],   red[0]+red[4]+red[8]+red[12]);
    atomicAdd(&stats[2*sA+1], red[1]+red[5]+red[9]+red[13]);
    if (boundary <= tileM + 127 && sA + 1 < BB) {
      atomicAdd(&stats[2*sA+2], red[2]+red[6]+red[10]+red[14]);
      atomicAdd(&stats[2*sA+3], red[3]+red[7]+red[11]+red[15]);
    }
  }
}

// ---------------- bf16 MFMA GEMM: out[M,N] = A[M,K] @ W[N,K]^T + bias (+skip)
// 128x128 tile, BK=32, global_load_lds width-16, XOR-swizzled LDS.
// bf16 output goes through an LDS-staged wide-store epilogue (full 64B sectors).
__global__ __launch_bounds__(256, 3) void gemm_bt(
    const __hip_bfloat16* __restrict__ A, const __hip_bfloat16* __restrict__ W,
    const float* __restrict__ bias, const float* __restrict__ skip,
    float* __restrict__ outF, __hip_bfloat16* __restrict__ outB,
    float* __restrict__ stats, int N, int K) {
  __shared__ __align__(16) union SM {
    unsigned short ab[2][128*32];   // As, Bs (main loop)
    unsigned short c[128*136];      // epilogue staging, stride 136 (272B, 16B-aligned)
  } sm;
  unsigned short* As = sm.ab[0];
  unsigned short* Bs = sm.ab[1];
  const int tileM = blockIdx.y * 128;
  const int tileN = blockIdx.x * 128;
  const int tid  = threadIdx.x;
  const int lane = tid & 63;
  const int wave = tid >> 6;
  const int wrow = (wave >> 1) * 64;
  const int wcol = (wave & 1) * 64;
  const int lm = lane & 15;
  const int lq = lane >> 4;

  const int r0 = tid >> 2;
  const int c0 = (tid & 3) ^ ((r0 >> 1) & 3);
  const __hip_bfloat16* a0p = A + (size_t)(tileM + r0) * K + c0 * 8;
  const __hip_bfloat16* a1p = A + (size_t)(tileM + 64 + r0) * K + c0 * 8;
  const __hip_bfloat16* b0p = W + (size_t)(tileN + r0) * K + c0 * 8;
  const __hip_bfloat16* b1p = W + (size_t)(tileN + 64 + r0) * K + c0 * 8;
  unsigned short* as0 = As + tid * 8;
  unsigned short* as1 = As + 2048 + tid * 8;
  unsigned short* bs0 = Bs + tid * 8;
  unsigned short* bs1 = Bs + 2048 + tid * 8;
  const int fc = (lq ^ ((lm >> 1) & 3)) * 8;

  floatx4 acc[4][4];
  #pragma unroll
  for (int i = 0; i < 4; ++i)
    #pragma unroll
    for (int j = 0; j < 4; ++j) acc[i][j] = (floatx4)0.0f;

  for (int k0 = 0; k0 < K; k0 += 32) {
    __syncthreads();
    glds16(a0p + k0, as0);
    glds16(a1p + k0, as1);
    glds16(b0p + k0, bs0);
    glds16(b1p + k0, bs1);
    __syncthreads();
    bf16x8 af[4], bfr[4];
    #pragma unroll
    for (int i = 0; i < 4; ++i) af[i]  = *(const bf16x8*)&As[(wrow + i*16 + lm)*32 + fc];
    #pragma unroll
    for (int j = 0; j < 4; ++j) bfr[j] = *(const bf16x8*)&Bs[(wcol + j*16 + lm)*32 + fc];
    #pragma unroll
    for (int i = 0; i < 4; ++i)
      #pragma unroll
      for (int j = 0; j < 4; ++j)
        acc[i][j] = __builtin_amdgcn_mfma_f32_16x16x32_bf16(af[i], bfr[j], acc[i][j], 0, 0, 0);
  }

  const int rq = lq * 4;
  if (outF) {
    const int sA = tileM / SS;
    const int boundary = (sA + 1) * SS;
    float p0s = 0.f, p0q = 0.f, p1s = 0.f, p1q = 0.f;
    #pragma unroll
    for (int j = 0; j < 4; ++j) {
      int n = tileN + wcol + j*16 + lm;
      float bj = bias[n];
      #pragma unroll
      for (int i = 0; i < 4; ++i) {
        int mb = tileM + wrow + i*16 + rq;
        #pragma unroll
        for (int r = 0; r < 4; ++r) {
          int row = mb + r;
          size_t o = (size_t)row * N + n;
          float v = acc[i][j][r] + bj;
          if (skip) v += skip[o];
          outF[o] = v;
          if (stats) {
            if (row < boundary) { p0s += v; p0q += v*v; }
            else                { p1s += v; p1q += v*v; }
          }
        }
      }
    }
    if (stats) {
      #pragma unroll
      for (int off = 32; off; off >>= 1) {
        p0s += __shfl_down(p0s, off); p0q += __shfl_down(p0q, off);
        p1s += __shfl_down(p1s, off); p1q += __shfl_down(p1q, off);
      }
      __syncthreads();
      float* red = (float*)sm.c;
      if (lane == 0) {
        red[wave*4+0] = p0s; red[wave*4+1] = p0q;
        red[wave*4+2] = p1s; red[wave*4+3] = p1q;
      }
      __syncthreads();
      if (tid == 0) {
        atomicAdd(&stats[2*sA],   red[0]+red[4]+red[8]+red[12]);
        atomicAdd(&stats[2*sA+1], red[1]+red[5]+red[9]+red[13]);
        if (boundary <= tileM + 127 && sA + 1 < BB) {
          atomicAdd(&stats[2*sA+2], red[2]+red[6]+red[10]+red[14]);
          atomicAdd(&stats[2*sA+3], red[3]+red[7]+red[11]+red[15]);
        }
      }
    }
  } else {
    // bf16 output: stage tile in LDS, then 16B/lane coalesced stores
    __syncthreads();
    #pragma unroll
    for (int j = 0; j < 4; ++j) {
      int n = wcol + j*16 + lm;
      float bj = bias[tileN + n];
      #pragma unroll
      for (int i = 0; i < 4; ++i) {
        int rowb = wrow + i*16 + rq;
        #pragma unroll
        for (int r = 0; r < 4; ++r)
          sm.c[(rowb + r)*136 + n] = bfbits(acc[i][j][r] + bj);
      }
    }
    __syncthreads();
    #pragma unroll
    for (int f = tid; f < 2048; f += 256) {
      int row = f >> 4, ch = (f & 15) * 8;
      *(uint4*)(outB + (size_t)(tileM + row) * N + tileN + ch) =
          *(const uint4*)&sm.c[row*136 + ch];
    }
  }
}

// ---------------- LN apply (stats = per-sample {sum, sumsq})
__global__ __launch_bounds__(256) void ln_apply(const float* __restrict__ in,
    const float* __restrict__ stats, const float* __restrict__ w,
    const float* __restrict__ bias, __hip_bfloat16* __restrict__ outB,
    float* __restrict__ outF) {
  int idx = blockIdx.x * 256 + threadIdx.x;      // float4 index, total 64*SE/4
  int samp = idx / (SE/4);
  int pos  = idx - samp * (SE/4);
  float S1 = stats[samp*2], S2 = stats[samp*2+1];
  float mu = S1 * (1.0f/SE);
  float var = S2 * (1.0f/SE) - mu*mu;
  float rstd = rsqrtf(var + 1e-5f);
  float4 v  = ((const float4*)in)[idx];
  float4 w4 = ((const float4*)w)[pos];
  float4 b4 = ((const float4*)bias)[pos];
  float4 r;
  r.x = (v.x - mu)*rstd*w4.x + b4.x;
  r.y = (v.y - mu)*rstd*w4.y + b4.y;
  r.z = (v.z - mu)*rstd*w4.z + b4.z;
  r.w = (v.w - mu)*rstd*w4.w + b4.w;
  if (outF) {
    ((float4*)outF)[idx] = r;
  } else {
    ushort4 us;
    us.x = bfbits(r.x); us.y = bfbits(r.y);
    us.z = bfbits(r.z); us.w = bfbits(r.w);
    *(ushort4*)(outB + (size_t)idx * 4) = us;
  }
}

// ---------------- MFMA flash attention: one block per (b,h)
__device__ __forceinline__ int kv_byte(int row, int col) {
  int c8 = col >> 3;
  int swz = (c8 & 24) | ((c8 ^ row) & 7);
  return row*384 + swz*16 + (col & 7)*2;
}

__global__ __launch_bounds__(256) void attn_mfma(const __hip_bfloat16* __restrict__ qkv,
                                                 __hip_bfloat16* __restrict__ o) {
  extern __shared__ char smem[];
  unsigned short* Pb = (unsigned short*)(smem + 75264);   // stride 212 elems
  const int bh = blockIdx.x;
  const int b = bh >> 2, h = bh & 3;
  const int tid = threadIdx.x, lane = tid & 63, wave = tid >> 6;
  const int lm = lane & 15, lq = lane >> 4;

  {
    const __hip_bfloat16* kbase = qkv + (size_t)b*SS*2304 + EE + h*HD;
    for (int f = tid; f < 196*24; f += 256) {
      int row = f / 24, c8 = f % 24;
      uint4 v = *(const uint4*)(kbase + (size_t)row*2304 + c8*8);
      int swz = (c8 & 24) | ((c8 ^ row) & 7);
      *(uint4*)(smem + row*384 + swz*16) = v;
    }
  }
  __syncthreads();

  const float scale = 0.07216878364870323f;   // 1/sqrt(192)
  for (int qt = wave; qt < 13; qt += 4) {
    bf16x8 qf[6];
    const __hip_bfloat16* qrow = qkv + (size_t)(b*SS + qt*16 + lm)*2304 + h*HD + lq*8;
    #pragma unroll
    for (int c = 0; c < 6; ++c) qf[c] = *(const bf16x8*)(qrow + c*32);
    floatx4 acc[13];
    #pragma unroll
    for (int nt = 0; nt < 13; ++nt) acc[nt] = (floatx4)0.0f;
    #pragma unroll
    for (int nt = 0; nt < 13; ++nt) {
      int n = nt*16 + lm;
      #pragma unroll
      for (int c = 0; c < 6; ++c) {
        bf16x8 kf = *(const bf16x8*)(smem + kv_byte(n, c*32 + lq*8));
        acc[nt] = __builtin_amdgcn_mfma_f32_16x16x32_bf16(qf[c], kf, acc[nt], 0, 0, 0);
      }
    }
    float rmax[4] = {-1e30f, -1e30f, -1e30f, -1e30f};
    #pragma unroll
    for (int nt = 0; nt < 13; ++nt) {
      bool valid = (nt < 12) | (lm < 4);
      #pragma unroll
      for (int r = 0; r < 4; ++r) {
        float v = acc[nt][r] * scale;
        acc[nt][r] = v;
        if (valid) rmax[r] = fmaxf(rmax[r], v);
      }
    }
    #pragma unroll
    for (int x = 1; x < 16; x <<= 1)
      #pragma unroll
      for (int r = 0; r < 4; ++r) rmax[r] = fmaxf(rmax[r], __shfl_xor(rmax[r], x));
    float rsum[4] = {0.f, 0.f, 0.f, 0.f};
    #pragma unroll
    for (int nt = 0; nt < 13; ++nt) {
      bool valid = (nt < 12) | (lm < 4);
      #pragma unroll
      for (int r = 0; r < 4; ++r) {
        float e = valid ? __expf(acc[nt][r] - rmax[r]) : 0.f;
        acc[nt][r] = e;
        rsum[r] += e;
      }
    }
    #pragma unroll
    for (int x = 1; x < 16; x <<= 1)
      #pragma unroll
      for (int r = 0; r < 4; ++r) rsum[r] += __shfl_xor(rsum[r], x);
    float inv[4];
    #pragma unroll
    for (int r = 0; r < 4; ++r) inv[r] = 1.0f / rsum[r];
    #pragma unroll
    for (int nt = 0; nt < 13; ++nt) {
      int col = nt*16 + lm;
      #pragma unroll
      for (int r = 0; r < 4; ++r) {
        int row = qt*16 + lq*4 + r;
        if (row < SS) {
          Pb[row*212 + col] = bfbits(acc[nt][r] * inv[r]);
        }
      }
    }
  }
  __syncthreads();

  {
    const __hip_bfloat16* vbase = qkv + (size_t)b*SS*2304 + 2*EE + h*HD;
    for (int f = tid; f < 196*24; f += 256) {
      int row = f / 24, c8 = f % 24;
      uint4 v = *(const uint4*)(vbase + (size_t)row*2304 + c8*8);
      int swz = (c8 & 24) | ((c8 ^ row) & 7);
      *(uint4*)(smem + row*384 + swz*16) = v;
    }
  }
  __syncthreads();

  const int d0 = wave * 48;
  union U8 { bf16x8 v; unsigned short u[8]; };
  U8 vf[3][6]; U8 vtail[3];
  #pragma unroll
  for (int nn = 0; nn < 3; ++nn) {
    int d = d0 + nn*16 + lm;
    #pragma unroll
    for (int c = 0; c < 6; ++c) {
      int sb = c*32 + lq*8;
      #pragma unroll
      for (int j = 0; j < 8; ++j)
        vf[nn][c].u[j] = *(const unsigned short*)(smem + kv_byte(sb + j, d));
    }
    #pragma unroll
    for (int j = 0; j < 8; ++j) vtail[nn].u[j] = 0;
    if (lane < 16) {
      #pragma unroll
      for (int j = 0; j < 4; ++j)
        vtail[nn].u[j] = *(const unsigned short*)(smem + kv_byte(192 + j, d0 + nn*16 + lane));
    }
  }

  for (int qt = 0; qt < 13; ++qt) {
    floatx4 O[3];
    #pragma unroll
    for (int nn = 0; nn < 3; ++nn) O[nn] = (floatx4)0.0f;
    #pragma unroll
    for (int c = 0; c < 6; ++c) {
      int e0 = (qt*16 + lm)*212 + c*32 + lq*8;
      bf16x4 lo = *(const bf16x4*)(Pb + e0);
      bf16x4 hi = *(const bf16x4*)(Pb + e0 + 4);
      bf16x8 pf = __builtin_shufflevector(lo, hi, 0, 1, 2, 3, 4, 5, 6, 7);
      #pragma unroll
      for (int nn = 0; nn < 3; ++nn)
        O[nn] = __builtin_amdgcn_mfma_f32_16x16x32_bf16(pf, vf[nn][c].v, O[nn], 0, 0, 0);
    }
    {
      U8 pt;
      #pragma unroll
      for (int j = 0; j < 8; ++j) pt.u[j] = 0;
      if (lane < 16) {
        #pragma unroll
        for (int j = 0; j < 4; ++j) pt.u[j] = Pb[(qt*16 + lane)*212 + 192 + j];
      }
      #pragma unroll
      for (int nn = 0; nn < 3; ++nn)
        O[nn] = __builtin_amdgcn_mfma_f32_16x16x32_bf16(pt.v, vtail[nn].v, O[nn], 0, 0, 0);
    }
    #pragma unroll
    for (int nn = 0; nn < 3; ++nn) {
      #pragma unroll
      for (int r = 0; r < 4; ++r) {
        int q = qt*16 + lq*4 + r;
        if (q < SS)
          o[(size_t)(b*SS + q)*EE + h*HD + d0 + nn*16 + lm] = __float2bfloat16(O[nn][r]);
      }
    }
  }
}

extern "C" void kernel_launch(void* const* d_in, const int* in_sizes, int n_in,
                              void* d_out, int out_size, void* d_ws, size_t ws_size,
                              hipStream_t stream) {
  const float* x      = (const float*)d_in[0];
  const float* conv_w = (const float*)d_in[1];
  const float* conv_b = (const float*)d_in[2];
  const float* wq = (const float*)d_in[3];
  const float* bq = (const float*)d_in[4];
  const float* wk = (const float*)d_in[5];
  const float* bk = (const float*)d_in[6];
  const float* wv = (const float*)d_in[7];
  const float* bv = (const float*)d_in[8];
  const float* wo = (const float*)d_in[9];
  const float* bo = (const float*)d_in[10];
  const float* ln1w = (const float*)d_in[11];
  const float* ln1b = (const float*)d_in[12];
  const float* ln2w = (const float*)d_in[13];
  const float* ln2b = (const float*)d_in[14];
  float* out = (float*)d_out;

  char* ws = (char*)d_ws;
  __hip_bfloat16* cw_b    = (__hip_bfloat16*)(ws + 19267584);     //  1179648
  __hip_bfloat16* qkvw_b  = (__hip_bfloat16*)(ws + 20447232);     //  3538944
  __hip_bfloat16* wo_b    = (__hip_bfloat16*)(ws + 23986176);     //  1179648
  float*          qkv_b   = (float*)         (ws + 25165824);     //     9216
  float*          emb     = (float*)         (ws + 25175040);     // 38535168
  __hip_bfloat16* hbuf    = (__hip_bfloat16*)(ws + 63710208);     // 19267584
  __hip_bfloat16* qkv     = (__hip_bfloat16*)(ws + 82977792);     // 57802752
  __hip_bfloat16* obuf    = (__hip_bfloat16*)(ws + 140780544);    // 19267584
  float*          stats   = (float*)(ws + 160048128);             //     1024

  // stats[0..127] = LN1 {sum,sumsq} per sample; stats[128..255] = LN2
  hipMemsetAsync(stats, 0, 1024, stream);
  convert_weights<<<2304, 256, 0, stream>>>(conv_w, wq, wk, wv, wo, bq, bk, bv,
                                            cw_b, qkvw_b, wo_b, qkv_b);
  // emb = patches(x) @ conv_w^T + conv_b (fp32) + fused LN1 stats
  gemm_patch<<<dim3(6, 98), 256, 0, stream>>>(x, cw_b, conv_b, emb, stats);
  ln_apply<<<BB*SE/4/256, 256, 0, stream>>>(emb, stats, ln1w, ln1b, hbuf, nullptr);
  gemm_bt<<<dim3(18, 98), 256, 0, stream>>>(hbuf, qkvw_b, qkv_b, nullptr, nullptr, qkv,
                                            nullptr, 3*EE, EE);
  hipFuncSetAttribute((const void*)attn_mfma,
                      hipFuncAttributeMaxDynamicSharedMemorySize, 163456);
  attn_mfma<<<BB*HH, 256, 163456, stream>>>(qkv, obuf);
  // out_pre = obuf @ wo^T + bo + emb (fp32) + fused LN2 stats
  gemm_bt<<<dim3(6, 98), 256, 0, stream>>>(obuf, wo_b, bo, emb, out, nullptr,
                                           stats + 128, EE, EE);
  ln_apply<<<BB*SE/4/256, 256, 0, stream>>>(out, stats + 128, ln2w, ln2b, nullptr, out);
}

// Round 6
// 338.948 us; speedup vs baseline: 3.5831x; 1.0396x over previous
//
#include <hip/hip_runtime.h>
#include <hip/hip_bf16.h>

#define GRID14 14
#define SS 196
#define EE 768
#define HH 4
#define HD 192
#define BB 64
#define MM (BB*SS)       // 12544
#define SE (SS*EE)       // 150528

typedef __bf16 bf16x8 __attribute__((ext_vector_type(8)));
typedef __bf16 bf16x4 __attribute__((ext_vector_type(4)));
typedef float floatx4 __attribute__((ext_vector_type(4)));

__device__ __forceinline__ void glds16(const void* g, void* l) {
  __builtin_amdgcn_global_load_lds(
      (const __attribute__((address_space(1))) unsigned int*)g,
      (__attribute__((address_space(3))) unsigned int*)l, 16, 0, 0);
}

__device__ __forceinline__ unsigned short bfbits(float f) {
  __hip_bfloat16 h = __float2bfloat16(f);
  return *(unsigned short*)&h;
}

// convert 8 consecutive fp32 -> 8 bf16, write 16B to LDS
__device__ __forceinline__ void cvt8(const float* __restrict__ g, unsigned short* l) {
  float4 f0 = *(const float4*)g;
  float4 f1 = *(const float4*)(g + 4);
  union { uint4 q; unsigned short u[8]; } t;
  t.u[0] = bfbits(f0.x); t.u[1] = bfbits(f0.y);
  t.u[2] = bfbits(f0.z); t.u[3] = bfbits(f0.w);
  t.u[4] = bfbits(f1.x); t.u[5] = bfbits(f1.y);
  t.u[6] = bfbits(f1.z); t.u[7] = bfbits(f1.w);
  *(uint4*)l = t.q;
}

// ---------------- weight conversion + QKV weight/bias concat + stats zeroing
__global__ __launch_bounds__(256) void convert_weights(
    const float* __restrict__ cw, const float* __restrict__ wq,
    const float* __restrict__ wk, const float* __restrict__ wv,
    const float* __restrict__ wo, const float* __restrict__ bq,
    const float* __restrict__ bk, const float* __restrict__ bv,
    __hip_bfloat16* __restrict__ cw_b, __hip_bfloat16* __restrict__ qkvw_b,
    __hip_bfloat16* __restrict__ wo_b, float* __restrict__ qkv_bias,
    float* __restrict__ stats) {
  int i = blockIdx.x * 256 + threadIdx.x;
  const int WN = EE * EE;
  if (i < WN) {
    cw_b[i] = __float2bfloat16(cw[i]);
    wo_b[i] = __float2bfloat16(wo[i]);
    qkvw_b[i]        = __float2bfloat16(wq[i]);
    qkvw_b[WN + i]   = __float2bfloat16(wk[i]);
    qkvw_b[2*WN + i] = __float2bfloat16(wv[i]);
  }
  if (i < EE) { qkv_bias[i] = bq[i]; qkv_bias[EE+i] = bk[i]; qkv_bias[2*EE+i] = bv[i]; }
  if (i < 256) stats[i] = 0.f;
}

// ======== shared GEMM pieces: 128x128 tile, BK=64, XOR-swizzled LDS ========
// LDS element layout: buf[row*64 + pc*8] holds source chunk c = pc ^ (row&7).
// Staging slot for thread t, part i: slot = 256*i + t -> row = (t>>3)+32i, pc = t&7.

// ---------------- emb GEMM with fused patch extraction + LN1 stats
__global__ __launch_bounds__(256, 3) void gemm_patch(
    const float* __restrict__ x, const __hip_bfloat16* __restrict__ W,
    const float* __restrict__ bias, float* __restrict__ outF,
    float* __restrict__ stats) {
  __shared__ __align__(16) unsigned short As[128*64];
  __shared__ __align__(16) unsigned short Bs[128*64];
  const int K = EE, N = EE;
  const int tileM = blockIdx.y * 128;
  const int tileN = blockIdx.x * 128;
  const int tid  = threadIdx.x;
  const int lane = tid & 63;
  const int wave = tid >> 6;
  const int wrow = (wave >> 1) * 64;
  const int wcol = (wave & 1) * 64;
  const int lm = lane & 15;
  const int lq = lane >> 4;

  const int rt = tid >> 3;               // base row 0..31
  const int pc = tid & 7;
  const int sc = pc ^ (rt & 7);          // source chunk (same for all 4 parts)
  // patch geometry for rows tileM + rt + 32*i
  const float* xb[4];
  #pragma unroll
  for (int i = 0; i < 4; ++i) {
    int m = tileM + rt + 32*i;
    int b = m / SS, s = m - b*SS;
    int gy = s / GRID14, gx = s - gy*GRID14;
    xb[i] = x + ((size_t)(b*3)*224 + gy*16)*224 + gx*16;
  }
  const __hip_bfloat16* bP = W + (size_t)(tileN + rt) * K + sc * 8;
  unsigned short* asl = As + tid * 8;
  unsigned short* bsl = Bs + tid * 8;
  const int f0 = lm & 7;

  floatx4 acc[4][4];
  #pragma unroll
  for (int i = 0; i < 4; ++i)
    #pragma unroll
    for (int j = 0; j < 4; ++j) acc[i][j] = (floatx4)0.0f;

  for (int k0 = 0; k0 < K; k0 += 64) {
    int k = k0 + sc*8;
    int off = (k >> 8)*50176 + ((k >> 4) & 15)*224 + (k & 15);
    __syncthreads();
    #pragma unroll
    for (int i = 0; i < 4; ++i) cvt8(xb[i] + off, asl + 2048*i);
    #pragma unroll
    for (int i = 0; i < 4; ++i) glds16(bP + k0 + (size_t)(32*i)*K, bsl + 2048*i);
    __syncthreads();
    #pragma unroll
    for (int h = 0; h < 2; ++h) {
      bf16x8 af[4], bfr[4];
      #pragma unroll
      for (int i = 0; i < 4; ++i)
        af[i]  = *(const bf16x8*)&As[(wrow + i*16 + lm)*64 + (((lq + 4*h) ^ f0))*8];
      #pragma unroll
      for (int j = 0; j < 4; ++j)
        bfr[j] = *(const bf16x8*)&Bs[(wcol + j*16 + lm)*64 + (((lq + 4*h) ^ f0))*8];
      #pragma unroll
      for (int i = 0; i < 4; ++i)
        #pragma unroll
        for (int j = 0; j < 4; ++j)
          acc[i][j] = __builtin_amdgcn_mfma_f32_16x16x32_bf16(af[i], bfr[j], acc[i][j], 0, 0, 0);
    }
  }

  const int rq = lq * 4;
  const int sA = tileM / SS;
  const int boundary = (sA + 1) * SS;
  float p0s = 0.f, p0q = 0.f, p1s = 0.f, p1q = 0.f;
  #pragma unroll
  for (int j = 0; j < 4; ++j) {
    int n = tileN + wcol + j*16 + lm;
    float bj = bias[n];
    #pragma unroll
    for (int i = 0; i < 4; ++i) {
      int mb = tileM + wrow + i*16 + rq;
      #pragma unroll
      for (int r = 0; r < 4; ++r) {
        int row = mb + r;
        float v = acc[i][j][r] + bj;
        outF[(size_t)row * N + n] = v;
        if (row < boundary) { p0s += v; p0q += v*v; }
        else                { p1s += v; p1q += v*v; }
      }
    }
  }
  #pragma unroll
  for (int off = 32; off; off >>= 1) {
    p0s += __shfl_down(p0s, off); p0q += __shfl_down(p0q, off);
    p1s += __shfl_down(p1s, off); p1q += __shfl_down(p1q, off);
  }
  __syncthreads();
  float* red = (float*)As;
  if (lane == 0) {
    red[wave*4+0] = p0s; red[wave*4+1] = p0q;
    red[wave*4+2] = p1s; red[wave*4+3] = p1q;
  }
  __syncthreads();
  if (tid == 0) {
    atomicAdd(&stats[2*sA],   red[0]+red[4]+red[8]+red[12]);
    atomicAdd(&stats[2*sA+1], red[1]+red[5]+red[9]+red[13]);
    if (boundary <= tileM + 127 && sA + 1 < BB) {
      atomicAdd(&stats[2*sA+2], red[2]+red[6]+red[10]+red[14]);
      atomicAdd(&stats[2*sA+3], red[3]+red[7]+red[11]+red[15]);
    }
  }
}

// ---------------- bf16 MFMA GEMM: out[M,N] = A[M,K] @ W[N,K]^T + bias (+skip)
// BK=64, global_load_lds width-16, XOR-swizzled. bf16 out via LDS-staged stores.
__global__ __launch_bounds__(256, 3) void gemm_bt(
    const __hip_bfloat16* __restrict__ A, const __hip_bfloat16* __restrict__ W,
    const float* __restrict__ bias, const float* __restrict__ skip,
    float* __restrict__ outF, __hip_bfloat16* __restrict__ outB,
    float* __restrict__ stats, int N, int K) {
  __shared__ __align__(16) union SM {
    unsigned short ab[2][128*64];   // As, Bs (main loop)  32 KB
    unsigned short c[128*136];      // epilogue staging    34816 B
  } sm;
  const int tileM = blockIdx.y * 128;
  const int tileN = blockIdx.x * 128;
  const int tid  = threadIdx.x;
  const int lane = tid & 63;
  const int wave = tid >> 6;
  const int wrow = (wave >> 1) * 64;
  const int wcol = (wave & 1) * 64;
  const int lm = lane & 15;
  const int lq = lane >> 4;

  const int rt = tid >> 3;
  const int pc = tid & 7;
  const int sc = pc ^ (rt & 7);
  const __hip_bfloat16* aP = A + (size_t)(tileM + rt) * K + sc * 8;
  const __hip_bfloat16* bP = W + (size_t)(tileN + rt) * K + sc * 8;
  unsigned short* asl = sm.ab[0] + tid * 8;
  unsigned short* bsl = sm.ab[1] + tid * 8;
  const int f0 = lm & 7;

  floatx4 acc[4][4];
  #pragma unroll
  for (int i = 0; i < 4; ++i)
    #pragma unroll
    for (int j = 0; j < 4; ++j) acc[i][j] = (floatx4)0.0f;

  for (int k0 = 0; k0 < K; k0 += 64) {
    __syncthreads();
    #pragma unroll
    for (int i = 0; i < 4; ++i) glds16(aP + k0 + (size_t)(32*i)*K, asl + 2048*i);
    #pragma unroll
    for (int i = 0; i < 4; ++i) glds16(bP + k0 + (size_t)(32*i)*K, bsl + 2048*i);
    __syncthreads();
    #pragma unroll
    for (int h = 0; h < 2; ++h) {
      bf16x8 af[4], bfr[4];
      #pragma unroll
      for (int i = 0; i < 4; ++i)
        af[i]  = *(const bf16x8*)&sm.ab[0][(wrow + i*16 + lm)*64 + (((lq + 4*h) ^ f0))*8];
      #pragma unroll
      for (int j = 0; j < 4; ++j)
        bfr[j] = *(const bf16x8*)&sm.ab[1][(wcol + j*16 + lm)*64 + (((lq + 4*h) ^ f0))*8];
      #pragma unroll
      for (int i = 0; i < 4; ++i)
        #pragma unroll
        for (int j = 0; j < 4; ++j)
          acc[i][j] = __builtin_amdgcn_mfma_f32_16x16x32_bf16(af[i], bfr[j], acc[i][j], 0, 0, 0);
    }
  }

  const int rq = lq * 4;
  if (outF) {
    const int sA = tileM / SS;
    const int boundary = (sA + 1) * SS;
    float p0s = 0.f, p0q = 0.f, p1s = 0.f, p1q = 0.f;
    #pragma unroll
    for (int j = 0; j < 4; ++j) {
      int n = tileN + wcol + j*16 + lm;
      float bj = bias[n];
      #pragma unroll
      for (int i = 0; i < 4; ++i) {
        int mb = tileM + wrow + i*16 + rq;
        #pragma unroll
        for (int r = 0; r < 4; ++r) {
          int row = mb + r;
          size_t o = (size_t)row * N + n;
          float v = acc[i][j][r] + bj;
          if (skip) v += skip[o];
          outF[o] = v;
          if (stats) {
            if (row < boundary) { p0s += v; p0q += v*v; }
            else                { p1s += v; p1q += v*v; }
          }
        }
      }
    }
    if (stats) {
      #pragma unroll
      for (int off = 32; off; off >>= 1) {
        p0s += __shfl_down(p0s, off); p0q += __shfl_down(p0q, off);
        p1s += __shfl_down(p1s, off); p1q += __shfl_down(p1q, off);
      }
      __syncthreads();
      float* red = (float*)sm.c;
      if (lane == 0) {
        red[wave*4+0] = p0s; red[wave*4+1] = p0q;
        red[wave*4+2] = p1s; red[wave*4+3] = p1q;
      }
      __syncthreads();
      if (tid == 0) {
        atomicAdd(&stats[2*sA],   red[0]+red[4]+red[8]+red[12]);
        atomicAdd(&stats[2*sA+1], red[1]+red[5]+red[9]+red[13]);
        if (boundary <= tileM + 127 && sA + 1 < BB) {
          atomicAdd(&stats[2*sA+2], red[2]+red[6]+red[10]+red[14]);
          atomicAdd(&stats[2*sA+3], red[3]+red[7]+red[11]+red[15]);
        }
      }
    }
  } else {
    // bf16 output: stage tile in LDS, then 16B/lane coalesced stores
    __syncthreads();
    #pragma unroll
    for (int j = 0; j < 4; ++j) {
      int n = wcol + j*16 + lm;
      float bj = bias[tileN + n];
      #pragma unroll
      for (int i = 0; i < 4; ++i) {
        int rowb = wrow + i*16 + rq;
        #pragma unroll
        for (int r = 0; r < 4; ++r)
          sm.c[(rowb + r)*136 + n] = bfbits(acc[i][j][r] + bj);
      }
    }
    __syncthreads();
    #pragma unroll
    for (int f = tid; f < 2048; f += 256) {
      int row = f >> 4, ch = (f & 15) * 8;
      *(uint4*)(outB + (size_t)(tileM + row) * N + tileN + ch) =
          *(const uint4*)&sm.c[row*136 + ch];
    }
  }
}

// ---------------- LN apply (stats = per-sample {sum, sumsq})
__global__ __launch_bounds__(256) void ln_apply(const float* __restrict__ in,
    const float* __restrict__ stats, const float* __restrict__ w,
    const float* __restrict__ bias, __hip_bfloat16* __restrict__ outB,
    float* __restrict__ outF) {
  int idx = blockIdx.x * 256 + threadIdx.x;      // float4 index, total 64*SE/4
  int samp = idx / (SE/4);
  int pos  = idx - samp * (SE/4);
  float S1 = stats[samp*2], S2 = stats[samp*2+1];
  float mu = S1 * (1.0f/SE);
  float var = S2 * (1.0f/SE) - mu*mu;
  float rstd = rsqrtf(var + 1e-5f);
  float4 v  = ((const float4*)in)[idx];
  float4 w4 = ((const float4*)w)[pos];
  float4 b4 = ((const float4*)bias)[pos];
  float4 r;
  r.x = (v.x - mu)*rstd*w4.x + b4.x;
  r.y = (v.y - mu)*rstd*w4.y + b4.y;
  r.z = (v.z - mu)*rstd*w4.z + b4.z;
  r.w = (v.w - mu)*rstd*w4.w + b4.w;
  if (outF) {
    ((float4*)outF)[idx] = r;
  } else {
    ushort4 us;
    us.x = bfbits(r.x); us.y = bfbits(r.y);
    us.z = bfbits(r.z); us.w = bfbits(r.w);
    *(ushort4*)(outB + (size_t)idx * 4) = us;
  }
}

// ---------------- MFMA flash attention: one block per (b,h)
__device__ __forceinline__ int kv_byte(int row, int col) {
  int c8 = col >> 3;
  int swz = (c8 & 24) | ((c8 ^ row) & 7);
  return row*384 + swz*16 + (col & 7)*2;
}

__global__ __launch_bounds__(256) void attn_mfma(const __hip_bfloat16* __restrict__ qkv,
                                                 __hip_bfloat16* __restrict__ o) {
  extern __shared__ char smem[];
  unsigned short* Pb = (unsigned short*)(smem + 75264);   // stride 212 elems
  const int bh = blockIdx.x;
  const int b = bh >> 2, h = bh & 3;
  const int tid = threadIdx.x, lane = tid & 63, wave = tid >> 6;
  const int lm = lane & 15, lq = lane >> 4;

  {
    const __hip_bfloat16* kbase = qkv + (size_t)b*SS*2304 + EE + h*HD;
    for (int f = tid; f < 196*24; f += 256) {
      int row = f / 24, c8 = f % 24;
      uint4 v = *(const uint4*)(kbase + (size_t)row*2304 + c8*8);
      int swz = (c8 & 24) | ((c8 ^ row) & 7);
      *(uint4*)(smem + row*384 + swz*16) = v;
    }
  }
  __syncthreads();

  const float scale = 0.07216878364870323f;   // 1/sqrt(192)
  for (int qt = wave; qt < 13; qt += 4) {
    bf16x8 qf[6];
    const __hip_bfloat16* qrow = qkv + (size_t)(b*SS + qt*16 + lm)*2304 + h*HD + lq*8;
    #pragma unroll
    for (int c = 0; c < 6; ++c) qf[c] = *(const bf16x8*)(qrow + c*32);
    floatx4 acc[13];
    #pragma unroll
    for (int nt = 0; nt < 13; ++nt) acc[nt] = (floatx4)0.0f;
    #pragma unroll
    for (int nt = 0; nt < 13; ++nt) {
      int n = nt*16 + lm;
      #pragma unroll
      for (int c = 0; c < 6; ++c) {
        bf16x8 kf = *(const bf16x8*)(smem + kv_byte(n, c*32 + lq*8));
        acc[nt] = __builtin_amdgcn_mfma_f32_16x16x32_bf16(qf[c], kf, acc[nt], 0, 0, 0);
      }
    }
    float rmax[4] = {-1e30f, -1e30f, -1e30f, -1e30f};
    #pragma unroll
    for (int nt = 0; nt < 13; ++nt) {
      bool valid = (nt < 12) | (lm < 4);
      #pragma unroll
      for (int r = 0; r < 4; ++r) {
        float v = acc[nt][r] * scale;
        acc[nt][r] = v;
        if (valid) rmax[r] = fmaxf(rmax[r], v);
      }
    }
    #pragma unroll
    for (int x = 1; x < 16; x <<= 1)
      #pragma unroll
      for (int r = 0; r < 4; ++r) rmax[r] = fmaxf(rmax[r], __shfl_xor(rmax[r], x));
    float rsum[4] = {0.f, 0.f, 0.f, 0.f};
    #pragma unroll
    for (int nt = 0; nt < 13; ++nt) {
      bool valid = (nt < 12) | (lm < 4);
      #pragma unroll
      for (int r = 0; r < 4; ++r) {
        float e = valid ? __expf(acc[nt][r] - rmax[r]) : 0.f;
        acc[nt][r] = e;
        rsum[r] += e;
      }
    }
    #pragma unroll
    for (int x = 1; x < 16; x <<= 1)
      #pragma unroll
      for (int r = 0; r < 4; ++r) rsum[r] += __shfl_xor(rsum[r], x);
    float inv[4];
    #pragma unroll
    for (int r = 0; r < 4; ++r) inv[r] = 1.0f / rsum[r];
    #pragma unroll
    for (int nt = 0; nt < 13; ++nt) {
      int col = nt*16 + lm;
      #pragma unroll
      for (int r = 0; r < 4; ++r) {
        int row = qt*16 + lq*4 + r;
        if (row < SS) {
          Pb[row*212 + col] = bfbits(acc[nt][r] * inv[r]);
        }
      }
    }
  }
  __syncthreads();

  {
    const __hip_bfloat16* vbase = qkv + (size_t)b*SS*2304 + 2*EE + h*HD;
    for (int f = tid; f < 196*24; f += 256) {
      int row = f / 24, c8 = f % 24;
      uint4 v = *(const uint4*)(vbase + (size_t)row*2304 + c8*8);
      int swz = (c8 & 24) | ((c8 ^ row) & 7);
      *(uint4*)(smem + row*384 + swz*16) = v;
    }
  }
  __syncthreads();

  const int d0 = wave * 48;
  union U8 { bf16x8 v; unsigned short u[8]; };
  U8 vf[3][6]; U8 vtail[3];
  #pragma unroll
  for (int nn = 0; nn < 3; ++nn) {
    int d = d0 + nn*16 + lm;
    #pragma unroll
    for (int c = 0; c < 6; ++c) {
      int sb = c*32 + lq*8;
      #pragma unroll
      for (int j = 0; j < 8; ++j)
        vf[nn][c].u[j] = *(const unsigned short*)(smem + kv_byte(sb + j, d));
    }
    #pragma unroll
    for (int j = 0; j < 8; ++j) vtail[nn].u[j] = 0;
    if (lane < 16) {
      #pragma unroll
      for (int j = 0; j < 4; ++j)
        vtail[nn].u[j] = *(const unsigned short*)(smem + kv_byte(192 + j, d0 + nn*16 + lane));
    }
  }

  for (int qt = 0; qt < 13; ++qt) {
    floatx4 O[3];
    #pragma unroll
    for (int nn = 0; nn < 3; ++nn) O[nn] = (floatx4)0.0f;
    #pragma unroll
    for (int c = 0; c < 6; ++c) {
      int e0 = (qt*16 + lm)*212 + c*32 + lq*8;
      bf16x4 lo = *(const bf16x4*)(Pb + e0);
      bf16x4 hi = *(const bf16x4*)(Pb + e0 + 4);
      bf16x8 pf = __builtin_shufflevector(lo, hi, 0, 1, 2, 3, 4, 5, 6, 7);
      #pragma unroll
      for (int nn = 0; nn < 3; ++nn)
        O[nn] = __builtin_amdgcn_mfma_f32_16x16x32_bf16(pf, vf[nn][c].v, O[nn], 0, 0, 0);
    }
    {
      U8 pt;
      #pragma unroll
      for (int j = 0; j < 8; ++j) pt.u[j] = 0;
      if (lane < 16) {
        #pragma unroll
        for (int j = 0; j < 4; ++j) pt.u[j] = Pb[(qt*16 + lane)*212 + 192 + j];
      }
      #pragma unroll
      for (int nn = 0; nn < 3; ++nn)
        O[nn] = __builtin_amdgcn_mfma_f32_16x16x32_bf16(pt.v, vtail[nn].v, O[nn], 0, 0, 0);
    }
    #pragma unroll
    for (int nn = 0; nn < 3; ++nn) {
      #pragma unroll
      for (int r = 0; r < 4; ++r) {
        int q = qt*16 + lq*4 + r;
        if (q < SS)
          o[(size_t)(b*SS + q)*EE + h*HD + d0 + nn*16 + lm] = __float2bfloat16(O[nn][r]);
      }
    }
  }
}

extern "C" void kernel_launch(void* const* d_in, const int* in_sizes, int n_in,
                              void* d_out, int out_size, void* d_ws, size_t ws_size,
                              hipStream_t stream) {
  const float* x      = (const float*)d_in[0];
  const float* conv_w = (const float*)d_in[1];
  const float* conv_b = (const float*)d_in[2];
  const float* wq = (const float*)d_in[3];
  const float* bq = (const float*)d_in[4];
  const float* wk = (const float*)d_in[5];
  const float* bk = (const float*)d_in[6];
  const float* wv = (const float*)d_in[7];
  const float* bv = (const float*)d_in[8];
  const float* wo = (const float*)d_in[9];
  const float* bo = (const float*)d_in[10];
  const float* ln1w = (const float*)d_in[11];
  const float* ln1b = (const float*)d_in[12];
  const float* ln2w = (const float*)d_in[13];
  const float* ln2b = (const float*)d_in[14];
  float* out = (float*)d_out;

  char* ws = (char*)d_ws;
  __hip_bfloat16* cw_b    = (__hip_bfloat16*)(ws + 19267584);     //  1179648
  __hip_bfloat16* qkvw_b  = (__hip_bfloat16*)(ws + 20447232);     //  3538944
  __hip_bfloat16* wo_b    = (__hip_bfloat16*)(ws + 23986176);     //  1179648
  float*          qkv_b   = (float*)         (ws + 25165824);     //     9216
  float*          emb     = (float*)         (ws + 25175040);     // 38535168
  __hip_bfloat16* hbuf    = (__hip_bfloat16*)(ws + 63710208);     // 19267584
  __hip_bfloat16* qkv     = (__hip_bfloat16*)(ws + 82977792);     // 57802752
  __hip_bfloat16* obuf    = (__hip_bfloat16*)(ws + 140780544);    // 19267584
  float*          stats   = (float*)(ws + 160048128);             //     1024

  // stats[0..127] = LN1 {sum,sumsq} per sample; stats[128..255] = LN2
  convert_weights<<<2304, 256, 0, stream>>>(conv_w, wq, wk, wv, wo, bq, bk, bv,
                                            cw_b, qkvw_b, wo_b, qkv_b, stats);
  // emb = patches(x) @ conv_w^T + conv_b (fp32) + fused LN1 stats
  gemm_patch<<<dim3(6, 98), 256, 0, stream>>>(x, cw_b, conv_b, emb, stats);
  ln_apply<<<BB*SE/4/256, 256, 0, stream>>>(emb, stats, ln1w, ln1b, hbuf, nullptr);
  gemm_bt<<<dim3(18, 98), 256, 0, stream>>>(hbuf, qkvw_b, qkv_b, nullptr, nullptr, qkv,
                                            nullptr, 3*EE, EE);
  hipFuncSetAttribute((const void*)attn_mfma,
                      hipFuncAttributeMaxDynamicSharedMemorySize, 163456);
  attn_mfma<<<BB*HH, 256, 163456, stream>>>(qkv, obuf);
  // out_pre = obuf @ wo^T + bo + emb (fp32) + fused LN2 stats
  gemm_bt<<<dim3(6, 98), 256, 0, stream>>>(obuf, wo_b, bo, emb, out, nullptr,
                                           stats + 128, EE, EE);
  ln_apply<<<BB*SE/4/256, 256, 0, stream>>>(out, stats + 128, ln2w, ln2b, nullptr, out);
}